// Round 1
// baseline (269.411 us; speedup 1.0000x reference)
//
#include <hip/hip_runtime.h>
#include <hip/hip_bf16.h>

#define B_ 4
#define L_ 32768
#define C_ 64
#define K_ 7
#define T_ 16378              // (L - 2K)/2 + 1
#define M_ (B_*T_)            // 65512 rows of (t-domain) data
#define TJ 16                 // output positions per block in kernel A
#define NJT 1024              // ceil(T_/TJ)
#define NBLKA (B_*NJT)        // 4096
#define TR 32                 // rows per block in kernel C
#define NBLKC ((M_+TR-1)/TR)  // 2048

// workspace layout in floats
#define OF_WT   0                        // repacked weights [c][n=d*7+kk], 64*448
#define OF_Y    28672                    // y_pre -> y_bn in place, M_*64
#define OF_Z    (OF_Y + M_*64)           // z_pre, M_*64
#define OF_PS1  (OF_Z + M_*64)
#define OF_PQ1  (OF_PS1 + NBLKA*64)
#define OF_PS2  (OF_PQ1 + NBLKA*64)
#define OF_PQ2  (OF_PS2 + NBLKC*64)
#define OF_C1   (OF_PQ2 + NBLKC*64)      // A1[64], BB1[64]
#define OF_C2   (OF_C1 + 128)            // A2[64], BB2[64]
// total ~9.2M floats ~36.8 MB

__device__ __forceinline__ float fast_tanh(float x) {
    x = fminf(15.f, fmaxf(-15.f, x));
    float e = __expf(2.f * x);
    return (e - 1.f) / (e + 1.f);
}

__device__ __forceinline__ float gelu_tanh(float v) {
    float u = 0.7978845608028654f * (v + 0.044715f * v * v * v);
    return 0.5f * v * (1.f + fast_tanh(u));
}

// repack weights (d,c,kk) -> Wt[c*448 + d*7+kk]
__global__ void kP(const float* __restrict__ w, float* __restrict__ Wt) {
    int i = blockIdx.x * 256 + threadIdx.x;
    if (i < 64 * 448) {
        int c = i / 448;
        int n = i - c * 448;
        int d = n / 7;
        int kk = n - d * 7;
        Wt[i] = w[(d * 64 + c) * 7 + kk];
    }
}

// fused: dynamic-weight GEMM + tanh + 14-tap contraction + residual + BN1 partials
__global__ __launch_bounds__(256) void kA(const float* __restrict__ x,
                                          const float* __restrict__ Wt,
                                          float* __restrict__ y,
                                          float* __restrict__ ps,
                                          float* __restrict__ pq) {
    __shared__ float xs[44 * 64];    // x rows [2j0 .. 2j0+43], 11.26 KB
    __shared__ float gs[32 * 448];   // tanh(G) rows l'=0..31, 57.3 KB
    __shared__ float red[2][4][64];

    const int tid = threadIdx.x;
    const int jt = blockIdx.x, b = blockIdx.y;
    const int j0 = jt * TJ;
    const int xrow0 = 2 * j0;
    const long xbase = (long)b * L_ * 64 + (long)xrow0 * 64;

    // stage x rows (guard tail past L)
    for (int i = tid; i < 44 * 64; i += 256) {
        int r = i >> 6;
        xs[i] = (xrow0 + r < L_) ? x[xbase + i] : 0.f;
    }
    __syncthreads();

    // GEMM: G[l', n] = sum_c V[l',c] * Wt[c][n],  V row l' = xs row 12+l'
    if (tid < 224) {
        const int n0 = tid * 2;
        float acc[32][2];
        #pragma unroll
        for (int l = 0; l < 32; ++l) { acc[l][0] = 0.f; acc[l][1] = 0.f; }
        for (int c0 = 0; c0 < 64; c0 += 4) {
            const float2 w0 = *(const float2*)&Wt[(c0 + 0) * 448 + n0];
            const float2 w1 = *(const float2*)&Wt[(c0 + 1) * 448 + n0];
            const float2 w2 = *(const float2*)&Wt[(c0 + 2) * 448 + n0];
            const float2 w3 = *(const float2*)&Wt[(c0 + 3) * 448 + n0];
            #pragma unroll
            for (int l = 0; l < 32; ++l) {
                const float4 v = *(const float4*)&xs[(12 + l) * 64 + c0];
                acc[l][0] += v.x * w0.x + v.y * w1.x + v.z * w2.x + v.w * w3.x;
                acc[l][1] += v.x * w0.y + v.y * w1.y + v.z * w2.y + v.w * w3.y;
            }
        }
        #pragma unroll
        for (int l = 0; l < 32; ++l) {
            float2 tg = make_float2(fast_tanh(acc[l][0]), fast_tanh(acc[l][1]));
            *(float2*)&gs[l * 448 + n0] = tg;
        }
    }
    __syncthreads();

    // epilogue: y[b,j,d] = x[12+2j,d] + sum_{kk,s} x[2j+2kk+s,d]*tanh(G[2j+s, d*7+kk])
    const int d = tid & 63, g = tid >> 6;
    float s = 0.f, s2 = 0.f;
    for (int jj = g; jj < TJ; jj += 4) {
        const int j = j0 + jj;
        if (j < T_) {
            float acc = xs[(12 + 2 * jj) * 64 + d];
            #pragma unroll
            for (int kk = 0; kk < K_; ++kk) {
                float g0 = gs[(2 * jj + 0) * 448 + d * 7 + kk];
                float g1 = gs[(2 * jj + 1) * 448 + d * 7 + kk];
                acc += xs[(2 * jj + 2 * kk) * 64 + d] * g0
                     + xs[(2 * jj + 2 * kk + 1) * 64 + d] * g1;
            }
            y[(long)(b * T_ + j) * 64 + d] = acc;
            s += acc;
            s2 += acc * acc;
        }
    }
    red[0][g][d] = s;
    red[1][g][d] = s2;
    __syncthreads();
    if (tid < 64) {
        float S = red[0][0][tid] + red[0][1][tid] + red[0][2][tid] + red[0][3][tid];
        float Q = red[1][0][tid] + red[1][1][tid] + red[1][2][tid] + red[1][3][tid];
        int blk = b * gridDim.x + jt;
        ps[blk * 64 + tid] = S;
        pq[blk * 64 + tid] = Q;
    }
}

// reduce per-channel partials -> affine coefficients A = rstd*scale, BB = bias - mean*A
__global__ void kB(const float* __restrict__ ps, const float* __restrict__ pq,
                   float* __restrict__ A, float* __restrict__ BB,
                   const float* __restrict__ scale, const float* __restrict__ bias,
                   int nblk, float invN) {
    const int c = blockIdx.x;
    float S = 0.f, Q = 0.f;
    for (int i = threadIdx.x; i < nblk; i += 256) {
        S += ps[i * 64 + c];
        Q += pq[i * 64 + c];
    }
    for (int o = 32; o > 0; o >>= 1) {
        S += __shfl_down(S, o);
        Q += __shfl_down(Q, o);
    }
    __shared__ float rs[4], rq[4];
    if ((threadIdx.x & 63) == 0) { rs[threadIdx.x >> 6] = S; rq[threadIdx.x >> 6] = Q; }
    __syncthreads();
    if (threadIdx.x == 0) {
        S = rs[0] + rs[1] + rs[2] + rs[3];
        Q = rq[0] + rq[1] + rq[2] + rq[3];
        float m = S * invN;
        float var = Q * invN - m * m;
        float rstd = rsqrtf(var + 1e-5f);
        float a = rstd * scale[c];
        A[c] = a;
        BB[c] = bias[c] - m * a;
    }
}

// BN1 apply (in place) + z = y_bn @ w_conv + BN2 partials
__global__ __launch_bounds__(256) void kC(float* __restrict__ y,
                                          const float* __restrict__ wconv,
                                          const float* __restrict__ A1,
                                          const float* __restrict__ B1,
                                          float* __restrict__ z,
                                          float* __restrict__ ps2,
                                          float* __restrict__ pq2) {
    __shared__ float wc[4096];   // w_conv [c][e]
    __shared__ float yl[TR * 64];
    __shared__ float red[2][4][64];
    const int tid = threadIdx.x;
    for (int i = tid; i < 4096; i += 256) wc[i] = wconv[i];
    const int row0 = blockIdx.x * TR;
    const int c = tid & 63;
    const float a1 = A1[c], b1 = B1[c];
    for (int i = tid; i < TR * 64; i += 256) {
        int r = i >> 6;
        long gr = row0 + r;
        float v = 0.f;
        if (gr < M_) {
            v = y[gr * 64 + c] * a1 + b1;
            y[gr * 64 + c] = v;
        }
        yl[i] = v;
    }
    __syncthreads();
    const int e = c, g = tid >> 6;
    float zacc[8];
    #pragma unroll
    for (int ri = 0; ri < 8; ++ri) zacc[ri] = 0.f;
    for (int c0 = 0; c0 < 64; c0 += 4) {
        const float w0 = wc[(c0 + 0) * 64 + e];
        const float w1 = wc[(c0 + 1) * 64 + e];
        const float w2 = wc[(c0 + 2) * 64 + e];
        const float w3 = wc[(c0 + 3) * 64 + e];
        #pragma unroll
        for (int ri = 0; ri < 8; ++ri) {
            const float4 v = *(const float4*)&yl[(g + ri * 4) * 64 + c0];
            zacc[ri] += v.x * w0 + v.y * w1 + v.z * w2 + v.w * w3;
        }
    }
    float s = 0.f, q = 0.f;
    #pragma unroll
    for (int ri = 0; ri < 8; ++ri) {
        long gr = row0 + g + ri * 4;
        if (gr < M_) {
            z[gr * 64 + e] = zacc[ri];
            s += zacc[ri];
            q += zacc[ri] * zacc[ri];
        }
    }
    red[0][g][e] = s;
    red[1][g][e] = q;
    __syncthreads();
    if (tid < 64) {
        float S = red[0][0][tid] + red[0][1][tid] + red[0][2][tid] + red[0][3][tid];
        float Q = red[1][0][tid] + red[1][1][tid] + red[1][2][tid] + red[1][3][tid];
        ps2[blockIdx.x * 64 + tid] = S;
        pq2[blockIdx.x * 64 + tid] = Q;
    }
}

// out = y_bn + gelu(z*A2 + BB2)
__global__ void kE(const float* __restrict__ y, const float* __restrict__ z,
                   const float* __restrict__ A2, const float* __restrict__ B2,
                   float* __restrict__ out, int N4) {
    int i = blockIdx.x * blockDim.x + threadIdx.x;
    const int stride = gridDim.x * blockDim.x;
    for (; i < N4; i += stride) {
        float4 yv = ((const float4*)y)[i];
        float4 zv = ((const float4*)z)[i];
        int cc = (i << 2) & 63;
        float4 a = *(const float4*)&A2[cc];
        float4 bb = *(const float4*)&B2[cc];
        float4 o;
        o.x = yv.x + gelu_tanh(zv.x * a.x + bb.x);
        o.y = yv.y + gelu_tanh(zv.y * a.y + bb.y);
        o.z = yv.z + gelu_tanh(zv.z * a.z + bb.z);
        o.w = yv.w + gelu_tanh(zv.w * a.w + bb.w);
        ((float4*)out)[i] = o;
    }
}

extern "C" void kernel_launch(void* const* d_in, const int* in_sizes, int n_in,
                              void* d_out, int out_size, void* d_ws, size_t ws_size,
                              hipStream_t stream) {
    const float* x       = (const float*)d_in[0];
    const float* weights = (const float*)d_in[1];
    const float* w_conv  = (const float*)d_in[2];
    const float* scale1  = (const float*)d_in[3];
    const float* bias1   = (const float*)d_in[4];
    const float* scale2  = (const float*)d_in[5];
    const float* bias2   = (const float*)d_in[6];
    float* out = (float*)d_out;
    float* ws  = (float*)d_ws;

    float* Wt  = ws + OF_WT;
    float* yb  = ws + OF_Y;
    float* zb  = ws + OF_Z;
    float* ps1 = ws + OF_PS1;
    float* pq1 = ws + OF_PQ1;
    float* ps2 = ws + OF_PS2;
    float* pq2 = ws + OF_PQ2;
    float* A1  = ws + OF_C1;
    float* BB1 = ws + OF_C1 + 64;
    float* A2  = ws + OF_C2;
    float* BB2 = ws + OF_C2 + 64;

    const float invN = 1.f / (float)M_;

    kP<<<112, 256, 0, stream>>>(weights, Wt);
    kA<<<dim3(NJT, B_), 256, 0, stream>>>(x, Wt, yb, ps1, pq1);
    kB<<<64, 256, 0, stream>>>(ps1, pq1, A1, BB1, scale1, bias1, NBLKA, invN);
    kC<<<NBLKC, 256, 0, stream>>>(yb, w_conv, A1, BB1, zb, ps2, pq2);
    kB<<<64, 256, 0, stream>>>(ps2, pq2, A2, BB2, scale2, bias2, NBLKC, invN);
    kE<<<2048, 256, 0, stream>>>(yb, zb, A2, BB2, out, M_ * 64 / 4);
}

// Round 2
// 159.143 us; speedup vs baseline: 1.6929x; 1.6929x over previous
//
#include <hip/hip_runtime.h>
#include <hip/hip_bf16.h>

#define B_ 4
#define L_ 32768
#define C_ 64
#define K_ 7
#define T_ 16378              // (L - 2K)/2 + 1
#define M_ (B_*T_)            // 65512 rows
#define TJ 16                 // output positions per block in kernel A
#define NJT 1024              // T_/TJ rounded up
#define NBLKA (B_*NJT)        // 4096
#define TR 32                 // rows per block in kernel C
#define NBLKC ((M_+TR-1)/TR)  // 2048

// workspace layout in floats
#define OF_WB   0                        // Wb fragments: 28672 ushorts = 14336 floats
#define OF_Y    28672                    // y_pre -> y_bn in place, M_*64
#define OF_Z    (OF_Y + M_*64)           // z_pre, M_*64
#define OF_PS1  (OF_Z + M_*64)
#define OF_PQ1  (OF_PS1 + NBLKA*64)
#define OF_PS2  (OF_PQ1 + NBLKA*64)
#define OF_PQ2  (OF_PS2 + NBLKC*64)
#define OF_C1   (OF_PQ2 + NBLKC*64)      // A1[64], BB1[64]
#define OF_C2   (OF_C1 + 128)            // A2[64], BB2[64]

typedef __attribute__((ext_vector_type(8))) short short8;
typedef __attribute__((ext_vector_type(4))) float f32x4;

__device__ __forceinline__ float fast_tanh(float x) {
    x = fminf(15.f, fmaxf(-15.f, x));
    float e = __expf(2.f * x);
    return (e - 1.f) / (e + 1.f);
}

__device__ __forceinline__ float gelu_tanh(float v) {
    float u = 0.7978845608028654f * (v + 0.044715f * v * v * v);
    return 0.5f * v * (1.f + fast_tanh(u));
}

__device__ __forceinline__ ushort f2bf(float f) {
    union { float f; unsigned u; } v; v.f = f;
    unsigned u = v.u + 0x7FFFu + ((v.u >> 16) & 1u);
    return (ushort)(u >> 16);
}

__device__ __forceinline__ float bf2f(unsigned hs) {
    union { unsigned u; float f; } v; v.u = hs << 16;
    return v.f;
}

// repack weights (d,c,kk) -> B-fragments Wb[(kt*28+nt)*64 + lane][j] (bf16)
// slot (bslot=lane>>4, j) <-> k = kt*32 + 8*bslot + j ; col n = nt*16 + (lane&15)
__global__ void kPb(const float* __restrict__ w, ushort* __restrict__ Wb) {
    int i = blockIdx.x * 256 + threadIdx.x;   // 28672 total
    int j = i & 7;
    int l = (i >> 3) & 63;
    int q = i >> 9;            // kt*28 + nt
    int nt = q % 28, kt = q / 28;
    int k = kt * 32 + 8 * (l >> 4) + j;       // channel c
    int n = nt * 16 + (l & 15);
    int d = n / 7, kk = n - 7 * d;
    Wb[i] = f2bf(w[(d * 64 + k) * 7 + kk]);
}

// fused: dyn-weight GEMM (MFMA bf16) + tanh + 14-tap contraction + residual + BN1 partials
__global__ __launch_bounds__(256) void kA(const float* __restrict__ x,
                                          const ushort* __restrict__ Wb,
                                          float* __restrict__ y,
                                          float* __restrict__ ps,
                                          float* __restrict__ pq) {
    __shared__ float  xsf[44 * 64];      // f32 x rows [2j0 .. 2j0+43]   (11.0 KB)
    __shared__ ushort xsb[32 * 64];      // bf16 GEMM rows (xs rows 12..43), swizzled (4 KB)
    __shared__ ushort gsT[448 * 34];     // tanh(G) transposed [n][l'], pad 34   (29.75 KB)
    __shared__ float  red[2][4][64];

    const int tid = threadIdx.x;
    const int jt = blockIdx.x, b = blockIdx.y;
    const int j0 = jt * TJ;
    const int xrow0 = 2 * j0;
    const long xbase = (long)b * L_ * 64 + (long)xrow0 * 64;

    // stage x rows (f32 + swizzled bf16 for GEMM)
    for (int i = tid; i < 44 * 64; i += 256) {
        int r = i >> 6;
        float v = (xrow0 + r < L_) ? x[xbase + i] : 0.f;
        xsf[i] = v;
        if (r >= 12) {
            int row = r - 12, c = i & 63;
            int byte = (row * 64 + c) * 2;
            byte ^= (row & 7) << 4;
            *(ushort*)((char*)xsb + byte) = f2bf(v);
        }
    }
    __syncthreads();

    // ---- MFMA GEMM: D[l'=0..31][n=0..447] = V[32x64] x Wt[64x448], tanh, -> gsT ----
    {
        const int w = tid >> 6;      // wave 0..3
        const int l = tid & 63;
        short8 a[2][2];
        #pragma unroll
        for (int mt = 0; mt < 2; ++mt)
            #pragma unroll
            for (int kt = 0; kt < 2; ++kt) {
                int row = mt * 16 + (l & 15);
                int byte = row * 128 + kt * 64 + (l >> 4) * 16;
                byte ^= (row & 7) << 4;
                a[mt][kt] = *(const short8*)((const char*)xsb + byte);
            }
        const int col = l & 15;
        const int r0 = 4 * (l >> 4);
        #pragma unroll
        for (int i = 0; i < 7; ++i) {
            const int nt = w + 4 * i;
            short8 b0 = *(const short8*)&Wb[(nt * 64 + l) * 8];
            short8 b1 = *(const short8*)&Wb[((28 + nt) * 64 + l) * 8];
            f32x4 acc0 = {0.f, 0.f, 0.f, 0.f};
            f32x4 acc1 = {0.f, 0.f, 0.f, 0.f};
            acc0 = __builtin_amdgcn_mfma_f32_16x16x32_bf16(a[0][0], b0, acc0, 0, 0, 0);
            acc0 = __builtin_amdgcn_mfma_f32_16x16x32_bf16(a[0][1], b1, acc0, 0, 0, 0);
            acc1 = __builtin_amdgcn_mfma_f32_16x16x32_bf16(a[1][0], b0, acc1, 0, 0, 0);
            acc1 = __builtin_amdgcn_mfma_f32_16x16x32_bf16(a[1][1], b1, acc1, 0, 0, 0);
            const int n = nt * 16 + col;
            // rows r0..r0+3 (acc0) and r0+16..r0+19 (acc1) of column n
            unsigned w00 = f2bf(fast_tanh(acc0[0])) | ((unsigned)f2bf(fast_tanh(acc0[1])) << 16);
            unsigned w01 = f2bf(fast_tanh(acc0[2])) | ((unsigned)f2bf(fast_tanh(acc0[3])) << 16);
            unsigned w10 = f2bf(fast_tanh(acc1[0])) | ((unsigned)f2bf(fast_tanh(acc1[1])) << 16);
            unsigned w11 = f2bf(fast_tanh(acc1[2])) | ((unsigned)f2bf(fast_tanh(acc1[3])) << 16);
            char* base = (char*)gsT + n * 68;
            *(unsigned*)(base + r0 * 2)      = w00;
            *(unsigned*)(base + r0 * 2 + 4)  = w01;
            *(unsigned*)(base + (r0 + 16) * 2)     = w10;
            *(unsigned*)(base + (r0 + 16) * 2 + 4) = w11;
        }
    }
    __syncthreads();

    // ---- epilogue: y = residual + 14-tap, + BN1 partials ----
    const int d = tid & 63, g = tid >> 6;
    float s = 0.f, q = 0.f;
    for (int jj = g; jj < TJ; jj += 4) {
        const int j = j0 + jj;
        if (j < T_) {
            float acc = xsf[(12 + 2 * jj) * 64 + d];
            #pragma unroll
            for (int kk = 0; kk < K_; ++kk) {
                unsigned gp = *(const unsigned*)((const char*)gsT + (d * 7 + kk) * 68 + jj * 4);
                float g0 = bf2f(gp & 0xffffu);
                float g1 = bf2f(gp >> 16);
                acc += xsf[(2 * jj + 2 * kk) * 64 + d] * g0
                     + xsf[(2 * jj + 2 * kk + 1) * 64 + d] * g1;
            }
            y[(long)(b * T_ + j) * 64 + d] = acc;
            s += acc;
            q += acc * acc;
        }
    }
    red[0][g][d] = s;
    red[1][g][d] = q;
    __syncthreads();
    if (tid < 64) {
        float S = red[0][0][tid] + red[0][1][tid] + red[0][2][tid] + red[0][3][tid];
        float Q = red[1][0][tid] + red[1][1][tid] + red[1][2][tid] + red[1][3][tid];
        int blk = b * gridDim.x + jt;
        ps[blk * 64 + tid] = S;
        pq[blk * 64 + tid] = Q;
    }
}

// reduce per-channel partials -> A = rstd*scale, BB = bias - mean*A
__global__ void kB(const float* __restrict__ ps, const float* __restrict__ pq,
                   float* __restrict__ A, float* __restrict__ BB,
                   const float* __restrict__ scale, const float* __restrict__ bias,
                   int nblk, float invN) {
    const int c = blockIdx.x;
    float S = 0.f, Q = 0.f;
    for (int i = threadIdx.x; i < nblk; i += 256) {
        S += ps[i * 64 + c];
        Q += pq[i * 64 + c];
    }
    for (int o = 32; o > 0; o >>= 1) {
        S += __shfl_down(S, o);
        Q += __shfl_down(Q, o);
    }
    __shared__ float rs[4], rq[4];
    if ((threadIdx.x & 63) == 0) { rs[threadIdx.x >> 6] = S; rq[threadIdx.x >> 6] = Q; }
    __syncthreads();
    if (threadIdx.x == 0) {
        S = rs[0] + rs[1] + rs[2] + rs[3];
        Q = rq[0] + rq[1] + rq[2] + rq[3];
        float m = S * invN;
        float var = Q * invN - m * m;
        float rstd = rsqrtf(var + 1e-5f);
        float a = rstd * scale[c];
        A[c] = a;
        BB[c] = bias[c] - m * a;
    }
}

// BN1 apply (in place) + z = y_bn @ w_conv + BN2 partials
__global__ __launch_bounds__(256) void kC(float* __restrict__ y,
                                          const float* __restrict__ wconv,
                                          const float* __restrict__ A1,
                                          const float* __restrict__ B1,
                                          float* __restrict__ z,
                                          float* __restrict__ ps2,
                                          float* __restrict__ pq2) {
    __shared__ float wc[4096];   // w_conv [c][e]
    __shared__ float yl[TR * 64];
    __shared__ float red[2][4][64];
    const int tid = threadIdx.x;
    for (int i = tid; i < 4096; i += 256) wc[i] = wconv[i];
    const int row0 = blockIdx.x * TR;
    const int c = tid & 63;
    const float a1 = A1[c], b1 = B1[c];
    for (int i = tid; i < TR * 64; i += 256) {
        int r = i >> 6;
        long gr = row0 + r;
        float v = 0.f;
        if (gr < M_) {
            v = y[gr * 64 + c] * a1 + b1;
            y[gr * 64 + c] = v;
        }
        yl[i] = v;
    }
    __syncthreads();
    const int e = c, g = tid >> 6;
    float zacc[8];
    #pragma unroll
    for (int ri = 0; ri < 8; ++ri) zacc[ri] = 0.f;
    for (int c0 = 0; c0 < 64; c0 += 4) {
        const float w0 = wc[(c0 + 0) * 64 + e];
        const float w1 = wc[(c0 + 1) * 64 + e];
        const float w2 = wc[(c0 + 2) * 64 + e];
        const float w3 = wc[(c0 + 3) * 64 + e];
        #pragma unroll
        for (int ri = 0; ri < 8; ++ri) {
            const float4 v = *(const float4*)&yl[(g + ri * 4) * 64 + c0];
            zacc[ri] += v.x * w0 + v.y * w1 + v.z * w2 + v.w * w3;
        }
    }
    float s = 0.f, q = 0.f;
    #pragma unroll
    for (int ri = 0; ri < 8; ++ri) {
        long gr = row0 + g + ri * 4;
        if (gr < M_) {
            z[gr * 64 + e] = zacc[ri];
            s += zacc[ri];
            q += zacc[ri] * zacc[ri];
        }
    }
    red[0][g][e] = s;
    red[1][g][e] = q;
    __syncthreads();
    if (tid < 64) {
        float S = red[0][0][tid] + red[0][1][tid] + red[0][2][tid] + red[0][3][tid];
        float Q = red[1][0][tid] + red[1][1][tid] + red[1][2][tid] + red[1][3][tid];
        ps2[blockIdx.x * 64 + tid] = S;
        pq2[blockIdx.x * 64 + tid] = Q;
    }
}

// out = y_bn + gelu(z*A2 + BB2)
__global__ void kE(const float* __restrict__ y, const float* __restrict__ z,
                   const float* __restrict__ A2, const float* __restrict__ B2,
                   float* __restrict__ out, int N4) {
    int i = blockIdx.x * blockDim.x + threadIdx.x;
    const int stride = gridDim.x * blockDim.x;
    for (; i < N4; i += stride) {
        float4 yv = ((const float4*)y)[i];
        float4 zv = ((const float4*)z)[i];
        int cc = (i << 2) & 63;
        float4 a = *(const float4*)&A2[cc];
        float4 bb = *(const float4*)&B2[cc];
        float4 o;
        o.x = yv.x + gelu_tanh(zv.x * a.x + bb.x);
        o.y = yv.y + gelu_tanh(zv.y * a.y + bb.y);
        o.z = yv.z + gelu_tanh(zv.z * a.z + bb.z);
        o.w = yv.w + gelu_tanh(zv.w * a.w + bb.w);
        ((float4*)out)[i] = o;
    }
}

extern "C" void kernel_launch(void* const* d_in, const int* in_sizes, int n_in,
                              void* d_out, int out_size, void* d_ws, size_t ws_size,
                              hipStream_t stream) {
    const float* x       = (const float*)d_in[0];
    const float* weights = (const float*)d_in[1];
    const float* w_conv  = (const float*)d_in[2];
    const float* scale1  = (const float*)d_in[3];
    const float* bias1   = (const float*)d_in[4];
    const float* scale2  = (const float*)d_in[5];
    const float* bias2   = (const float*)d_in[6];
    float* out = (float*)d_out;
    float* ws  = (float*)d_ws;

    ushort* Wb = (ushort*)(ws + OF_WB);
    float* yb  = ws + OF_Y;
    float* zb  = ws + OF_Z;
    float* ps1 = ws + OF_PS1;
    float* pq1 = ws + OF_PQ1;
    float* ps2 = ws + OF_PS2;
    float* pq2 = ws + OF_PQ2;
    float* A1  = ws + OF_C1;
    float* BB1 = ws + OF_C1 + 64;
    float* A2  = ws + OF_C2;
    float* BB2 = ws + OF_C2 + 64;

    const float invN = 1.f / (float)M_;

    kPb<<<112, 256, 0, stream>>>(weights, Wb);
    kA<<<dim3(NJT, B_), 256, 0, stream>>>(x, Wb, yb, ps1, pq1);
    kB<<<64, 256, 0, stream>>>(ps1, pq1, A1, BB1, scale1, bias1, NBLKA, invN);
    kC<<<NBLKC, 256, 0, stream>>>(yb, w_conv, A1, BB1, zb, ps2, pq2);
    kB<<<64, 256, 0, stream>>>(ps2, pq2, A2, BB2, scale2, bias2, NBLKC, invN);
    kE<<<2048, 256, 0, stream>>>(yb, zb, A2, BB2, out, M_ * 64 / 4);
}

// Round 3
// 78.288 us; speedup vs baseline: 3.4413x; 2.0328x over previous
//
#include <hip/hip_runtime.h>
#include <hip/hip_bf16.h>

#define B_ 4
#define L_ 32768
#define C_ 64
#define K_ 7
#define T_ 16378              // (L - 2K)/2 + 1
#define M_ (B_*T_)            // 65512 rows
#define TJ 16                 // output positions per block in kernel A
#define NJT 1024              // T_/TJ rounded up
#define NBLKA (B_*NJT)        // 4096
#define RZ 64                 // rows per block in kZ/kE
#define NBLKZ ((M_+RZ-1)/RZ)  // 1024

// workspace layout in floats
#define OF_WB   0                        // Wb fragments: 28672 ushorts = 14336 floats
#define OF_Y    28672                    // y_pre, M_*64
#define OF_PS1  (OF_Y + M_*64)
#define OF_PQ1  (OF_PS1 + NBLKA*64)
#define OF_PS2  (OF_PQ1 + NBLKA*64)
#define OF_PQ2  (OF_PS2 + NBLKZ*64)
#define OF_C1   (OF_PQ2 + NBLKZ*64)      // A1[64], BB1[64]
#define OF_C2   (OF_C1 + 128)            // A2[64], BB2[64]

typedef __attribute__((ext_vector_type(8))) short short8;
typedef __attribute__((ext_vector_type(4))) float f32x4;

__device__ __forceinline__ unsigned cvt_pk_bf16(float a, float b) {
    unsigned r;
    asm("v_cvt_pk_bf16_f32 %0, %1, %2" : "=v"(r) : "v"(a), "v"(b));
    return r;   // lo = bf16(a), hi = bf16(b)
}

__device__ __forceinline__ float fast_tanh(float x) {
    // 1 - 2/(1+e^{2x}); saturates correctly for |x| large (exp2->inf/0)
    float e = __builtin_amdgcn_exp2f(x * 2.885390082f);   // 2*log2(e)
    return __builtin_fmaf(-2.f, __builtin_amdgcn_rcpf(1.f + e), 1.f);
}

__device__ __forceinline__ float gelu_tanh(float v) {
    float u = 0.7978845608028654f * (v + 0.044715f * v * v * v);
    return 0.5f * v * (1.f + fast_tanh(u));
}

__device__ __forceinline__ float bflo(unsigned p) {
    union { unsigned u; float f; } v; v.u = p << 16; return v.f;
}
__device__ __forceinline__ float bfhi(unsigned p) {
    union { unsigned u; float f; } v; v.u = p & 0xffff0000u; return v.f;
}

// load bf16 from swizzled row-major LDS tile [row][c], stride 64 ch
__device__ __forceinline__ float bf_ld(const ushort* buf, int row, int c) {
    int byte = (row * 128 + c * 2) ^ ((row & 7) << 4);
    unsigned hs = *(const ushort*)((const char*)buf + byte);
    union { unsigned u; float f; } v; v.u = hs << 16; return v.f;
}

// repack weights (d,c,kk) -> B-fragments Wb[(kt*28+nt)*64 + lane][j] (bf16)
__global__ void kPb(const float* __restrict__ w, ushort* __restrict__ Wb) {
    int i = blockIdx.x * 256 + threadIdx.x;   // 28672 total
    int j = i & 7;
    int l = (i >> 3) & 63;
    int q = i >> 9;            // kt*28 + nt
    int nt = q % 28, kt = q / 28;
    int k = kt * 32 + 8 * (l >> 4) + j;       // channel c
    int n = nt * 16 + (l & 15);
    int d = n / 7, kk = n - 7 * d;
    Wb[i] = (ushort)(cvt_pk_bf16(w[(d * 64 + k) * 7 + kk], 0.f) & 0xffffu);
}

// fused: dyn-weight GEMM (MFMA bf16) + tanh + 14-tap contraction + residual + BN1 partials
__global__ __launch_bounds__(256) void kA(const float* __restrict__ x,
                                          const ushort* __restrict__ Wb,
                                          float* __restrict__ y,
                                          float* __restrict__ ps,
                                          float* __restrict__ pq) {
    __shared__ ushort xsb[44 * 64];      // bf16 x rows [2j0..2j0+43], swizzled (5.5 KB)
    __shared__ ushort gsT[448 * 34];     // tanh(G) transposed [n][l'], pad 34 (29.75 KB)
    __shared__ float  red[2][4][64];

    const int tid = threadIdx.x;
    const int jt = blockIdx.x, b = blockIdx.y;
    const int j0 = jt * TJ;
    const int xrow0 = 2 * j0;
    const float* xb = x + ((long)b * L_ + xrow0) * 64;

    // stage 44 rows of x as bf16, swizzled
    #pragma unroll
    for (int it = 0; it < 6; ++it) {
        int p = tid + it * 256;
        if (p < 44 * 32) {
            int row = p >> 5, c0 = (p & 31) * 2;
            float2 v = make_float2(0.f, 0.f);
            if (xrow0 + row < L_) v = *(const float2*)(xb + row * 64 + c0);
            unsigned pk = cvt_pk_bf16(v.x, v.y);
            int byte = (row * 128 + c0 * 2) ^ ((row & 7) << 4);
            *(unsigned*)((char*)xsb + byte) = pk;
        }
    }
    __syncthreads();

    // ---- MFMA GEMM: D[l'=0..31][n=0..447] = V[32x64] x Wt[64x448], tanh -> gsT ----
    {
        const int w = tid >> 6;      // wave 0..3
        const int l = tid & 63;
        short8 afr[2][2];
        #pragma unroll
        for (int mt = 0; mt < 2; ++mt)
            #pragma unroll
            for (int kt = 0; kt < 2; ++kt) {
                int row = 12 + mt * 16 + (l & 15);
                int byte = (row * 128 + kt * 64 + (l >> 4) * 16) ^ ((row & 7) << 4);
                afr[mt][kt] = *(const short8*)((const char*)xsb + byte);
            }
        const int col = l & 15;
        const int r0 = 4 * (l >> 4);
        for (int i = 0; i < 7; ++i) {
            const int nt = w + 4 * i;
            short8 b0 = *(const short8*)&Wb[(nt * 64 + l) * 8];
            short8 b1 = *(const short8*)&Wb[((28 + nt) * 64 + l) * 8];
            f32x4 acc0 = {0.f, 0.f, 0.f, 0.f};
            f32x4 acc1 = {0.f, 0.f, 0.f, 0.f};
            acc0 = __builtin_amdgcn_mfma_f32_16x16x32_bf16(afr[0][0], b0, acc0, 0, 0, 0);
            acc0 = __builtin_amdgcn_mfma_f32_16x16x32_bf16(afr[0][1], b1, acc0, 0, 0, 0);
            acc1 = __builtin_amdgcn_mfma_f32_16x16x32_bf16(afr[1][0], b0, acc1, 0, 0, 0);
            acc1 = __builtin_amdgcn_mfma_f32_16x16x32_bf16(afr[1][1], b1, acc1, 0, 0, 0);
            const int n = nt * 16 + col;
            unsigned w00 = cvt_pk_bf16(fast_tanh(acc0[0]), fast_tanh(acc0[1]));
            unsigned w01 = cvt_pk_bf16(fast_tanh(acc0[2]), fast_tanh(acc0[3]));
            unsigned w10 = cvt_pk_bf16(fast_tanh(acc1[0]), fast_tanh(acc1[1]));
            unsigned w11 = cvt_pk_bf16(fast_tanh(acc1[2]), fast_tanh(acc1[3]));
            char* base = (char*)gsT + n * 68;
            *(unsigned*)(base + r0 * 2)            = w00;
            *(unsigned*)(base + r0 * 2 + 4)        = w01;
            *(unsigned*)(base + (r0 + 16) * 2)     = w10;
            *(unsigned*)(base + (r0 + 16) * 2 + 4) = w11;
        }
    }
    __syncthreads();

    // ---- epilogue: y = residual + 14-tap, + BN1 partials ----
    const int d = tid & 63, g = tid >> 6;
    float s = 0.f, q = 0.f;
    for (int jj = g; jj < TJ; jj += 4) {
        const int j = j0 + jj;
        if (j < T_) {
            float acc = bf_ld(xsb, 12 + 2 * jj, d);
            #pragma unroll
            for (int kk = 0; kk < K_; ++kk) {
                unsigned gp = *(const unsigned*)((const char*)gsT + (d * 7 + kk) * 68 + jj * 4);
                int r = 2 * jj + 2 * kk;
                acc += bf_ld(xsb, r, d) * bflo(gp) + bf_ld(xsb, r + 1, d) * bfhi(gp);
            }
            y[((long)(b * T_ + j)) * 64 + d] = acc;
            s += acc;
            q += acc * acc;
        }
    }
    red[0][g][d] = s;
    red[1][g][d] = q;
    __syncthreads();
    if (tid < 64) {
        float S = red[0][0][tid] + red[0][1][tid] + red[0][2][tid] + red[0][3][tid];
        float Q = red[1][0][tid] + red[1][1][tid] + red[1][2][tid] + red[1][3][tid];
        int blk = b * gridDim.x + jt;
        ps[blk * 64 + tid] = S;
        pq[blk * 64 + tid] = Q;
    }
}

// reduce per-channel partials -> A = rstd*scale, BB = bias - mean*A
__global__ void kB(const float* __restrict__ ps, const float* __restrict__ pq,
                   float* __restrict__ A, float* __restrict__ BB,
                   const float* __restrict__ scale, const float* __restrict__ bias,
                   int nblk, float invN) {
    const int c = blockIdx.x;
    float S = 0.f, Q = 0.f;
    for (int i = threadIdx.x; i < nblk; i += 256) {
        S += ps[i * 64 + c];
        Q += pq[i * 64 + c];
    }
    for (int o = 32; o > 0; o >>= 1) {
        S += __shfl_down(S, o);
        Q += __shfl_down(Q, o);
    }
    __shared__ float rs[4], rq[4];
    if ((threadIdx.x & 63) == 0) { rs[threadIdx.x >> 6] = S; rq[threadIdx.x >> 6] = Q; }
    __syncthreads();
    if (threadIdx.x == 0) {
        S = rs[0] + rs[1] + rs[2] + rs[3];
        Q = rq[0] + rq[1] + rq[2] + rq[3];
        float m = S * invN;
        float var = Q * invN - m * m;
        float rstd = rsqrtf(var + 1e-5f);
        float a = rstd * scale[c];
        A[c] = a;
        BB[c] = bias[c] - m * a;
    }
}

// shared device helper: stage y tile (bf16, swizzled) + A1-folded w_conv B-frags
__device__ __forceinline__ void stage_yz(const float* __restrict__ y,
                                         const float* __restrict__ wconv,
                                         const float* __restrict__ A1,
                                         ushort* ys, ushort* wb,
                                         long row0, int tid) {
    #pragma unroll
    for (int it = 0; it < 8; ++it) {
        int p = tid + it * 256;            // p < RZ*32 = 2048
        int row = p >> 5, c0 = (p & 31) * 2;
        long gr = row0 + row;
        float2 v = make_float2(0.f, 0.f);
        if (gr < M_) v = *(const float2*)(y + gr * 64 + c0);
        unsigned pk = cvt_pk_bf16(v.x, v.y);
        int byte = (row * 128 + c0 * 2) ^ ((row & 7) << 4);
        *(unsigned*)((char*)ys + byte) = pk;
    }
    #pragma unroll
    for (int it = 0; it < 16; ++it) {
        int i = tid + it * 256;            // i < 4096
        int j = i & 7, lane = (i >> 3) & 63, q2 = i >> 9;
        int kt = q2 >> 2, nt = q2 & 3;
        int c = kt * 32 + 8 * (lane >> 4) + j;
        int e = nt * 16 + (lane & 15);
        float wv = A1[c] * wconv[c * 64 + e];
        wb[i] = (ushort)(cvt_pk_bf16(wv, 0.f) & 0xffffu);
    }
}

// pass 2a: z' = y_pre @ (A1 .* w_conv), BN2 partials only (no z write)
__global__ __launch_bounds__(256) void kZ(const float* __restrict__ y,
                                          const float* __restrict__ wconv,
                                          const float* __restrict__ A1,
                                          float* __restrict__ ps2,
                                          float* __restrict__ pq2) {
    __shared__ ushort ys[RZ * 64];     // 8 KB
    __shared__ ushort wb[8 * 64 * 8];  // 8 KB (B-frags: [kt*4+nt][lane][j])
    __shared__ float red[2][4][64];
    const int tid = threadIdx.x;
    const long row0 = (long)blockIdx.x * RZ;
    stage_yz(y, wconv, A1, ys, wb, row0, tid);
    __syncthreads();

    const int w = tid >> 6, l = tid & 63;
    short8 bf[4][2];
    #pragma unroll
    for (int nt = 0; nt < 4; ++nt)
        #pragma unroll
        for (int kt = 0; kt < 2; ++kt)
            bf[nt][kt] = *(const short8*)&wb[((kt * 4 + nt) * 64 + l) * 8];

    const int mt = w;
    int rowg = mt * 16 + (l & 15);
    short8 a0 = *(const short8*)((const char*)ys + ((rowg * 128 + (l >> 4) * 16) ^ ((rowg & 7) << 4)));
    short8 a1 = *(const short8*)((const char*)ys + ((rowg * 128 + 64 + (l >> 4) * 16) ^ ((rowg & 7) << 4)));

    float s[4], q[4];
    #pragma unroll
    for (int nt = 0; nt < 4; ++nt) { s[nt] = 0.f; q[nt] = 0.f; }
    #pragma unroll
    for (int nt = 0; nt < 4; ++nt) {
        f32x4 acc = {0.f, 0.f, 0.f, 0.f};
        acc = __builtin_amdgcn_mfma_f32_16x16x32_bf16(a0, bf[nt][0], acc, 0, 0, 0);
        acc = __builtin_amdgcn_mfma_f32_16x16x32_bf16(a1, bf[nt][1], acc, 0, 0, 0);
        #pragma unroll
        for (int i = 0; i < 4; ++i) { s[nt] += acc[i]; q[nt] += acc[i] * acc[i]; }
    }
    // rows past M_ are zero-staged -> z'=0 -> contribute 0 to partials
    #pragma unroll
    for (int nt = 0; nt < 4; ++nt) {
        float ss = s[nt], qq = q[nt];
        ss += __shfl_xor(ss, 16); ss += __shfl_xor(ss, 32);
        qq += __shfl_xor(qq, 16); qq += __shfl_xor(qq, 32);
        if (l < 16) { red[0][w][nt * 16 + l] = ss; red[1][w][nt * 16 + l] = qq; }
    }
    __syncthreads();
    if (tid < 64) {
        float S = red[0][0][tid] + red[0][1][tid] + red[0][2][tid] + red[0][3][tid];
        float Q = red[1][0][tid] + red[1][1][tid] + red[1][2][tid] + red[1][3][tid];
        ps2[blockIdx.x * 64 + tid] = S;
        pq2[blockIdx.x * 64 + tid] = Q;
    }
}

// pass 2b: recompute z' (bitwise-identical), out = (A1*y+BB1) + gelu(A2*z'+BB2)
__global__ __launch_bounds__(256) void kE(const float* __restrict__ y,
                                          const float* __restrict__ wconv,
                                          const float* __restrict__ A1,
                                          const float* __restrict__ B1,
                                          const float* __restrict__ A2,
                                          const float* __restrict__ B2,
                                          float* __restrict__ out) {
    __shared__ ushort ys[RZ * 64];
    __shared__ ushort wb[8 * 64 * 8];
    __shared__ float cf[4][64];
    const int tid = threadIdx.x;
    const long row0 = (long)blockIdx.x * RZ;
    stage_yz(y, wconv, A1, ys, wb, row0, tid);
    {
        int c = tid & 63, a = tid >> 6;
        const float* srcs[4] = {A1, B1, A2, B2};
        cf[a][c] = srcs[a][c];
    }
    __syncthreads();

    const int w = tid >> 6, l = tid & 63;
    short8 bf[4][2];
    #pragma unroll
    for (int nt = 0; nt < 4; ++nt)
        #pragma unroll
        for (int kt = 0; kt < 2; ++kt)
            bf[nt][kt] = *(const short8*)&wb[((kt * 4 + nt) * 64 + l) * 8];

    const int mt = w;
    int rowg = mt * 16 + (l & 15);
    short8 a0 = *(const short8*)((const char*)ys + ((rowg * 128 + (l >> 4) * 16) ^ ((rowg & 7) << 4)));
    short8 a1 = *(const short8*)((const char*)ys + ((rowg * 128 + 64 + (l >> 4) * 16) ^ ((rowg & 7) << 4)));

    #pragma unroll
    for (int nt = 0; nt < 4; ++nt) {
        f32x4 acc = {0.f, 0.f, 0.f, 0.f};
        acc = __builtin_amdgcn_mfma_f32_16x16x32_bf16(a0, bf[nt][0], acc, 0, 0, 0);
        acc = __builtin_amdgcn_mfma_f32_16x16x32_bf16(a1, bf[nt][1], acc, 0, 0, 0);
        const int e = nt * 16 + (l & 15);
        const float a1c = cf[0][e], b1c = cf[1][e];
        const float a2c = cf[2][e], b2c = cf[3][e];
        #pragma unroll
        for (int i = 0; i < 4; ++i) {
            int rloc = mt * 16 + 4 * (l >> 4) + i;
            long gr = row0 + rloc;
            if (gr < M_) {
                float yb = bf_ld(ys, rloc, e);
                float zb = a2c * acc[i] + b2c;
                out[gr * 64 + e] = (a1c * yb + b1c) + gelu_tanh(zb);
            }
        }
    }
}

extern "C" void kernel_launch(void* const* d_in, const int* in_sizes, int n_in,
                              void* d_out, int out_size, void* d_ws, size_t ws_size,
                              hipStream_t stream) {
    const float* x       = (const float*)d_in[0];
    const float* weights = (const float*)d_in[1];
    const float* w_conv  = (const float*)d_in[2];
    const float* scale1  = (const float*)d_in[3];
    const float* bias1   = (const float*)d_in[4];
    const float* scale2  = (const float*)d_in[5];
    const float* bias2   = (const float*)d_in[6];
    float* out = (float*)d_out;
    float* ws  = (float*)d_ws;

    ushort* Wb = (ushort*)(ws + OF_WB);
    float* yb  = ws + OF_Y;
    float* ps1 = ws + OF_PS1;
    float* pq1 = ws + OF_PQ1;
    float* ps2 = ws + OF_PS2;
    float* pq2 = ws + OF_PQ2;
    float* A1  = ws + OF_C1;
    float* BB1 = ws + OF_C1 + 64;
    float* A2  = ws + OF_C2;
    float* BB2 = ws + OF_C2 + 64;

    const float invN = 1.f / (float)M_;

    kPb<<<112, 256, 0, stream>>>(weights, Wb);
    kA<<<dim3(NJT, B_), 256, 0, stream>>>(x, Wb, yb, ps1, pq1);
    kB<<<64, 256, 0, stream>>>(ps1, pq1, A1, BB1, scale1, bias1, NBLKA, invN);
    kZ<<<NBLKZ, 256, 0, stream>>>(yb, w_conv, A1, ps2, pq2);
    kB<<<64, 256, 0, stream>>>(ps2, pq2, A2, BB2, scale2, bias2, NBLKZ, invN);
    kE<<<NBLKZ, 256, 0, stream>>>(yb, w_conv, A1, BB1, A2, BB2, out);
}

// Round 4
// 73.298 us; speedup vs baseline: 3.6755x; 1.0681x over previous
//
#include <hip/hip_runtime.h>
#include <hip/hip_bf16.h>

#define B_ 4
#define L_ 32768
#define C_ 64
#define K_ 7
#define T_ 16378              // (L - 2K)/2 + 1
#define M_ (B_*T_)            // 65512 rows
#define TJ 16                 // output positions per block in kernel A
#define NJT 1024              // T_/TJ rounded up
#define NBLKA (B_*NJT)        // 4096
#define RZ 64                 // rows per block in kZ/kE
#define NBLKZ ((M_+RZ-1)/RZ)  // 1024

// workspace layout in floats
#define OF_WB   0                        // Wb fragments: 28672 ushorts = 14336 floats
#define OF_Y    14336                    // y bf16: M_*64 ushorts = M_*32 floats
#define OF_PS1  (OF_Y + M_*32)           // [c][NBLKA]
#define OF_PQ1  (OF_PS1 + 64*NBLKA)
#define OF_PS2  (OF_PQ1 + 64*NBLKA)      // [c][NBLKZ]
#define OF_PQ2  (OF_PS2 + 64*NBLKZ)
#define OF_C1   (OF_PQ2 + 64*NBLKZ)      // A1[64], BB1[64]
#define OF_C2   (OF_C1 + 128)            // A2[64], BB2[64]

typedef __attribute__((ext_vector_type(8))) short short8;
typedef __attribute__((ext_vector_type(4))) float f32x4;

__device__ __forceinline__ unsigned cvt_pk_bf16(float a, float b) {
    unsigned r;
    asm("v_cvt_pk_bf16_f32 %0, %1, %2" : "=v"(r) : "v"(a), "v"(b));
    return r;   // lo = bf16(a), hi = bf16(b)
}

__device__ __forceinline__ float fast_tanh(float x) {
    // 1 - 2/(1+e^{2x}); saturates correctly for |x| large
    float e = __builtin_amdgcn_exp2f(x * 2.885390082f);   // 2*log2(e)
    return __builtin_fmaf(-2.f, __builtin_amdgcn_rcpf(1.f + e), 1.f);
}

__device__ __forceinline__ float gelu_tanh(float v) {
    float u = 0.7978845608028654f * (v + 0.044715f * v * v * v);
    return 0.5f * v * (1.f + fast_tanh(u));
}

__device__ __forceinline__ float bflo(unsigned p) {
    union { unsigned u; float f; } v; v.u = p << 16; return v.f;
}
__device__ __forceinline__ float bfhi(unsigned p) {
    union { unsigned u; float f; } v; v.u = p & 0xffff0000u; return v.f;
}
__device__ __forceinline__ float bfu(ushort h) {
    union { unsigned u; float f; } v; v.u = ((unsigned)h) << 16; return v.f;
}

// load bf16 from swizzled row-major LDS tile [row][c] (16B-block XOR swizzle)
__device__ __forceinline__ float bf_ld(const ushort* buf, int row, int c) {
    int byte = (row * 128 + c * 2) ^ ((row & 7) << 4);
    return bfu(*(const ushort*)((const char*)buf + byte));
}

// repack weights (d,c,kk) -> B-fragments Wb[(kt*28+nt)*64 + lane][j] (bf16)
__global__ void kPb(const float* __restrict__ w, ushort* __restrict__ Wb) {
    int i = blockIdx.x * 256 + threadIdx.x;   // 28672 total
    int j = i & 7;
    int l = (i >> 3) & 63;
    int q = i >> 9;            // kt*28 + nt
    int nt = q % 28, kt = q / 28;
    int k = kt * 32 + 8 * (l >> 4) + j;       // channel c
    int n = nt * 16 + (l & 15);
    int d = n / 7, kk = n - 7 * d;
    Wb[i] = (ushort)(cvt_pk_bf16(w[(d * 64 + k) * 7 + kk], 0.f) & 0xffffu);
}

// fused: dyn-weight GEMM (MFMA bf16) + tanh + 14-tap contraction + residual + BN1 partials
__global__ __launch_bounds__(256) void kA(const float* __restrict__ x,
                                          const ushort* __restrict__ Wb,
                                          ushort* __restrict__ y,
                                          float* __restrict__ ps,
                                          float* __restrict__ pq) {
    __shared__ ushort xp[22 * 128];      // pair-major [rp][c][s] bf16, 5.5 KB
    __shared__ ushort gsT[448 * 34];     // tanh(G) transposed [n][l'], pad 34 (29.75 KB)
    __shared__ float  red[2][4][64];

    const int tid = threadIdx.x;
    const int jt = blockIdx.x, b = blockIdx.y;
    const int j0 = jt * TJ;
    const int xrow0 = 2 * j0;
    const float* xb = x + (long)b * L_ * 64;

    // ---- stage x rows [xrow0 .. xrow0+43] in pair-major bf16 (clamped; tail unused) ----
    #pragma unroll
    for (int it = 0; it < 3; ++it) {
        int p = tid + it * 256;
        if (p < 704) {                       // 22 rowpairs * 32
            int rp = p >> 5, c0 = (p & 31) * 2;
            int r0 = xrow0 + 2 * rp;
            int r1 = min(r0 + 1, L_ - 1);
            r0 = min(r0, L_ - 1);
            float2 va = *(const float2*)(xb + (long)r0 * 64 + c0);
            float2 vb = *(const float2*)(xb + (long)r1 * 64 + c0);
            uint2 wv;
            wv.x = cvt_pk_bf16(va.x, vb.x);
            wv.y = cvt_pk_bf16(va.y, vb.y);
            *(uint2*)((char*)xp + rp * 256 + c0 * 4) = wv;
        }
    }

    // ---- A-fragments straight from global f32 (L2-hot) ----
    const int l = tid & 63;
    short8 afr[2][2];
    #pragma unroll
    for (int mt = 0; mt < 2; ++mt)
        #pragma unroll
        for (int kt = 0; kt < 2; ++kt) {
            int row = min(xrow0 + 12 + mt * 16 + (l & 15), L_ - 1);
            const float* pr = xb + (long)row * 64 + kt * 32 + (l >> 4) * 8;
            float4 v0 = *(const float4*)pr;
            float4 v1 = *(const float4*)(pr + 4);
            uint4 u;
            u.x = cvt_pk_bf16(v0.x, v0.y);
            u.y = cvt_pk_bf16(v0.z, v0.w);
            u.z = cvt_pk_bf16(v1.x, v1.y);
            u.w = cvt_pk_bf16(v1.z, v1.w);
            afr[mt][kt] = *(short8*)&u;
        }

    // ---- MFMA GEMM: D[l'=0..31][n=0..447], tanh -> gsT ----
    {
        const int w = tid >> 6;
        const int col = l & 15;
        const int r0 = 4 * (l >> 4);
        for (int i = 0; i < 7; ++i) {
            const int nt = w + 4 * i;
            short8 b0 = *(const short8*)&Wb[(nt * 64 + l) * 8];
            short8 b1 = *(const short8*)&Wb[((28 + nt) * 64 + l) * 8];
            f32x4 acc0 = {0.f, 0.f, 0.f, 0.f};
            f32x4 acc1 = {0.f, 0.f, 0.f, 0.f};
            acc0 = __builtin_amdgcn_mfma_f32_16x16x32_bf16(afr[0][0], b0, acc0, 0, 0, 0);
            acc0 = __builtin_amdgcn_mfma_f32_16x16x32_bf16(afr[0][1], b1, acc0, 0, 0, 0);
            acc1 = __builtin_amdgcn_mfma_f32_16x16x32_bf16(afr[1][0], b0, acc1, 0, 0, 0);
            acc1 = __builtin_amdgcn_mfma_f32_16x16x32_bf16(afr[1][1], b1, acc1, 0, 0, 0);
            const int n = nt * 16 + col;
            char* base = (char*)gsT + n * 68;
            *(unsigned*)(base + r0 * 2)            = cvt_pk_bf16(fast_tanh(acc0[0]), fast_tanh(acc0[1]));
            *(unsigned*)(base + r0 * 2 + 4)        = cvt_pk_bf16(fast_tanh(acc0[2]), fast_tanh(acc0[3]));
            *(unsigned*)(base + (r0 + 16) * 2)     = cvt_pk_bf16(fast_tanh(acc1[0]), fast_tanh(acc1[1]));
            *(unsigned*)(base + (r0 + 16) * 2 + 4) = cvt_pk_bf16(fast_tanh(acc1[2]), fast_tanh(acc1[3]));
        }
    }
    __syncthreads();   // xp + gsT now visible

    // ---- epilogue: y = residual + 14-tap (immediate-offset LDS reads) + BN1 partials ----
    const int d = l, g = tid >> 6;
    float S = 0.f, Q = 0.f;
    #pragma unroll
    for (int ii = 0; ii < 4; ++ii) {
        const int jj = g + 4 * ii;
        const int j = j0 + jj;
        float acc = bfu(*(const ushort*)((const char*)xp + (6 + jj) * 256 + d * 4));
        const char* xbp = (const char*)xp + jj * 256 + d * 4;
        const char* gbp = (const char*)gsT + d * 476 + jj * 4;
        #pragma unroll
        for (int kk = 0; kk < K_; ++kk) {
            unsigned xpr = *(const unsigned*)(xbp + kk * 256);
            unsigned gp  = *(const unsigned*)(gbp + kk * 68);
            acc += bflo(xpr) * bflo(gp) + bfhi(xpr) * bfhi(gp);
        }
        float other = __shfl_xor(acc, 1);
        if (j < T_) {
            if ((d & 1) == 0) {
                unsigned pk = cvt_pk_bf16(acc, other);
                *(unsigned*)((char*)y + ((long)(b * T_ + j)) * 128 + d * 2) = pk;
            }
            S += acc;
            Q += acc * acc;
        }
    }
    red[0][g][d] = S;
    red[1][g][d] = Q;
    __syncthreads();
    if (tid < 64) {
        float S4 = red[0][0][tid] + red[0][1][tid] + red[0][2][tid] + red[0][3][tid];
        float Q4 = red[1][0][tid] + red[1][1][tid] + red[1][2][tid] + red[1][3][tid];
        int blk = b * NJT + jt;
        ps[tid * NBLKA + blk] = S4;
        pq[tid * NBLKA + blk] = Q4;
    }
}

// reduce transposed per-channel partials -> A = rstd*scale, BB = bias - mean*A
__global__ void kB(const float* __restrict__ ps, const float* __restrict__ pq,
                   float* __restrict__ A, float* __restrict__ BB,
                   const float* __restrict__ scale, const float* __restrict__ bias,
                   int nblk, float invN) {
    const int c = blockIdx.x;
    const float* bs = ps + (long)c * nblk;
    const float* bq = pq + (long)c * nblk;
    float S = 0.f, Q = 0.f;
    for (int i = threadIdx.x; i < nblk; i += 256) {
        S += bs[i];
        Q += bq[i];
    }
    for (int o = 32; o > 0; o >>= 1) {
        S += __shfl_down(S, o);
        Q += __shfl_down(Q, o);
    }
    __shared__ float rs[4], rq[4];
    if ((threadIdx.x & 63) == 0) { rs[threadIdx.x >> 6] = S; rq[threadIdx.x >> 6] = Q; }
    __syncthreads();
    if (threadIdx.x == 0) {
        S = rs[0] + rs[1] + rs[2] + rs[3];
        Q = rq[0] + rq[1] + rq[2] + rq[3];
        float m = S * invN;
        float var = Q * invN - m * m;
        float rstd = rsqrtf(var + 1e-5f);
        float a = rstd * scale[c];
        A[c] = a;
        BB[c] = bias[c] - m * a;
    }
}

// stage y tile (bf16 global -> swizzled LDS, pure copy) ; zero-fill OOB rows
__device__ __forceinline__ void stage_y(const ushort* __restrict__ y,
                                        ushort* ys, long row0, int tid) {
    #pragma unroll
    for (int it = 0; it < 2; ++it) {
        int p = tid + it * 256;          // p < 512 = RZ*8
        int row = p >> 3, c16 = (p & 7) * 16;
        long gr = row0 + row;
        uint4 v = make_uint4(0, 0, 0, 0);
        if (gr < M_) v = *(const uint4*)((const char*)y + gr * 128 + c16);
        *(uint4*)((char*)ys + ((row * 128 + c16) ^ ((row & 7) << 4))) = v;
    }
}

// stage A1-folded w_conv B-fragments
__device__ __forceinline__ void stage_w(const float* __restrict__ wconv,
                                        const float* __restrict__ A1,
                                        ushort* wb, int tid) {
    #pragma unroll
    for (int it = 0; it < 16; ++it) {
        int i = tid + it * 256;          // i < 4096
        int j = i & 7, lane = (i >> 3) & 63, q2 = i >> 9;
        int kt = q2 >> 2, nt = q2 & 3;
        int c = kt * 32 + 8 * (lane >> 4) + j;
        int e = nt * 16 + (lane & 15);
        wb[i] = (ushort)(cvt_pk_bf16(A1[c] * wconv[c * 64 + e], 0.f) & 0xffffu);
    }
}

// pass 2a: z' = y_bf16 @ (A1 .* w_conv), BN2 partials only
__global__ __launch_bounds__(256) void kZ(const ushort* __restrict__ y,
                                          const float* __restrict__ wconv,
                                          const float* __restrict__ A1,
                                          float* __restrict__ ps2,
                                          float* __restrict__ pq2) {
    __shared__ ushort ys[RZ * 64];     // 8 KB
    __shared__ ushort wb[8 * 64 * 8];  // 8 KB
    __shared__ float red[2][4][64];
    const int tid = threadIdx.x;
    const long row0 = (long)blockIdx.x * RZ;
    stage_y(y, ys, row0, tid);
    stage_w(wconv, A1, wb, tid);
    __syncthreads();

    const int w = tid >> 6, l = tid & 63;
    short8 bf[4][2];
    #pragma unroll
    for (int nt = 0; nt < 4; ++nt)
        #pragma unroll
        for (int kt = 0; kt < 2; ++kt)
            bf[nt][kt] = *(const short8*)&wb[((kt * 4 + nt) * 64 + l) * 8];

    int rowg = w * 16 + (l & 15);
    short8 a0 = *(const short8*)((const char*)ys + ((rowg * 128 + (l >> 4) * 16) ^ ((rowg & 7) << 4)));
    short8 a1 = *(const short8*)((const char*)ys + ((rowg * 128 + 64 + (l >> 4) * 16) ^ ((rowg & 7) << 4)));

    #pragma unroll
    for (int nt = 0; nt < 4; ++nt) {
        f32x4 acc = {0.f, 0.f, 0.f, 0.f};
        acc = __builtin_amdgcn_mfma_f32_16x16x32_bf16(a0, bf[nt][0], acc, 0, 0, 0);
        acc = __builtin_amdgcn_mfma_f32_16x16x32_bf16(a1, bf[nt][1], acc, 0, 0, 0);
        float ss = 0.f, qq = 0.f;
        #pragma unroll
        for (int i = 0; i < 4; ++i) { ss += acc[i]; qq += acc[i] * acc[i]; }
        ss += __shfl_xor(ss, 16); ss += __shfl_xor(ss, 32);
        qq += __shfl_xor(qq, 16); qq += __shfl_xor(qq, 32);
        if (l < 16) { red[0][w][nt * 16 + l] = ss; red[1][w][nt * 16 + l] = qq; }
    }
    __syncthreads();
    if (tid < 64) {
        float S = red[0][0][tid] + red[0][1][tid] + red[0][2][tid] + red[0][3][tid];
        float Q = red[1][0][tid] + red[1][1][tid] + red[1][2][tid] + red[1][3][tid];
        ps2[tid * NBLKZ + blockIdx.x] = S;
        pq2[tid * NBLKZ + blockIdx.x] = Q;
    }
}

// pass 2b: recompute z' (identical), out = (A1*y+BB1) + gelu(A2*z'+BB2)
__global__ __launch_bounds__(256) void kE(const ushort* __restrict__ y,
                                          const float* __restrict__ wconv,
                                          const float* __restrict__ A1,
                                          const float* __restrict__ B1,
                                          const float* __restrict__ A2,
                                          const float* __restrict__ B2,
                                          float* __restrict__ out) {
    __shared__ ushort ys[RZ * 64];
    __shared__ ushort wb[8 * 64 * 8];
    __shared__ float cf[4][64];
    const int tid = threadIdx.x;
    const long row0 = (long)blockIdx.x * RZ;
    stage_y(y, ys, row0, tid);
    stage_w(wconv, A1, wb, tid);
    {
        int c = tid & 63, a = tid >> 6;
        const float* srcs[4] = {A1, B1, A2, B2};
        cf[a][c] = srcs[a][c];
    }
    __syncthreads();

    const int w = tid >> 6, l = tid & 63;
    short8 bf[4][2];
    #pragma unroll
    for (int nt = 0; nt < 4; ++nt)
        #pragma unroll
        for (int kt = 0; kt < 2; ++kt)
            bf[nt][kt] = *(const short8*)&wb[((kt * 4 + nt) * 64 + l) * 8];

    int rowg = w * 16 + (l & 15);
    short8 a0 = *(const short8*)((const char*)ys + ((rowg * 128 + (l >> 4) * 16) ^ ((rowg & 7) << 4)));
    short8 a1 = *(const short8*)((const char*)ys + ((rowg * 128 + 64 + (l >> 4) * 16) ^ ((rowg & 7) << 4)));

    #pragma unroll
    for (int nt = 0; nt < 4; ++nt) {
        f32x4 acc = {0.f, 0.f, 0.f, 0.f};
        acc = __builtin_amdgcn_mfma_f32_16x16x32_bf16(a0, bf[nt][0], acc, 0, 0, 0);
        acc = __builtin_amdgcn_mfma_f32_16x16x32_bf16(a1, bf[nt][1], acc, 0, 0, 0);
        const int e = nt * 16 + (l & 15);
        const float a1c = cf[0][e], b1c = cf[1][e];
        const float a2c = cf[2][e], b2c = cf[3][e];
        #pragma unroll
        for (int i = 0; i < 4; ++i) {
            int rloc = w * 16 + 4 * (l >> 4) + i;
            long gr = row0 + rloc;
            if (gr < M_) {
                float yb = bf_ld(ys, rloc, e);
                float zb = a2c * acc[i] + b2c;
                out[gr * 64 + e] = (a1c * yb + b1c) + gelu_tanh(zb);
            }
        }
    }
}

extern "C" void kernel_launch(void* const* d_in, const int* in_sizes, int n_in,
                              void* d_out, int out_size, void* d_ws, size_t ws_size,
                              hipStream_t stream) {
    const float* x       = (const float*)d_in[0];
    const float* weights = (const float*)d_in[1];
    const float* w_conv  = (const float*)d_in[2];
    const float* scale1  = (const float*)d_in[3];
    const float* bias1   = (const float*)d_in[4];
    const float* scale2  = (const float*)d_in[5];
    const float* bias2   = (const float*)d_in[6];
    float* out = (float*)d_out;
    float* ws  = (float*)d_ws;

    ushort* Wb = (ushort*)(ws + OF_WB);
    ushort* yb = (ushort*)(ws + OF_Y);
    float* ps1 = ws + OF_PS1;
    float* pq1 = ws + OF_PQ1;
    float* ps2 = ws + OF_PS2;
    float* pq2 = ws + OF_PQ2;
    float* A1  = ws + OF_C1;
    float* BB1 = ws + OF_C1 + 64;
    float* A2  = ws + OF_C2;
    float* BB2 = ws + OF_C2 + 64;

    const float invN = 1.f / (float)M_;

    kPb<<<112, 256, 0, stream>>>(weights, Wb);
    kA<<<dim3(NJT, B_), 256, 0, stream>>>(x, Wb, yb, ps1, pq1);
    kB<<<64, 256, 0, stream>>>(ps1, pq1, A1, BB1, scale1, bias1, NBLKA, invN);
    kZ<<<NBLKZ, 256, 0, stream>>>(yb, w_conv, A1, ps2, pq2);
    kB<<<64, 256, 0, stream>>>(ps2, pq2, A2, BB2, scale2, bias2, NBLKZ, invN);
    kE<<<NBLKZ, 256, 0, stream>>>(yb, w_conv, A1, BB1, A2, BB2, out);
}

// Round 5
// 60.791 us; speedup vs baseline: 4.4317x; 1.2057x over previous
//
#include <hip/hip_runtime.h>
#include <hip/hip_bf16.h>

#define B_ 4
#define L_ 32768
#define C_ 64
#define K_ 7
#define T_ 16378              // (L - 2K)/2 + 1
#define M_ (B_*T_)            // 65512 rows
#define TJ 16                 // output positions per j-tile
#define IT 4                  // j-tiles per kA block
#define NJB 256               // grid.x of kA  (NJB*IT*TJ = 16384 >= T_)
#define NBLKA (B_*NJB)        // 1024 partial sets
#define NBZ 512               // kZ blocks (x128 rows)
#define NBE 1024              // kE blocks (x64 rows)

// workspace layout in floats
#define OF_WB   0                        // Wb: 28672 ushorts = 14336 floats
#define OF_WB2  14336                    // Wb2: 4096 ushorts = 2048 floats
#define OF_Y    16384                    // y bf16: M_*64 ushorts = M_*32 floats
#define OF_PS1  (OF_Y + M_*32)           // [c][NBLKA]
#define OF_PQ1  (OF_PS1 + 64*NBLKA)
#define OF_PS2  (OF_PQ1 + 64*NBLKA)      // [c][NBZ]
#define OF_PQ2  (OF_PS2 + 64*NBZ)
#define OF_C1   (OF_PQ2 + 64*NBZ)        // A1[64], BB1[64]
#define OF_C2   (OF_C1 + 128)            // A2[64], BB2[64]

typedef __attribute__((ext_vector_type(8))) short short8;
typedef __attribute__((ext_vector_type(4))) float f32x4;

__device__ __forceinline__ unsigned cvt_pk_bf16(float a, float b) {
    unsigned r;
    asm("v_cvt_pk_bf16_f32 %0, %1, %2" : "=v"(r) : "v"(a), "v"(b));
    return r;   // lo = bf16(a), hi = bf16(b)
}

__device__ __forceinline__ float fast_tanh(float x) {
    float e = __builtin_amdgcn_exp2f(x * 2.885390082f);   // 2*log2(e)
    return __builtin_fmaf(-2.f, __builtin_amdgcn_rcpf(1.f + e), 1.f);
}

__device__ __forceinline__ float gelu_tanh(float v) {
    float u = 0.7978845608028654f * (v + 0.044715f * v * v * v);
    return 0.5f * v * (1.f + fast_tanh(u));
}

__device__ __forceinline__ float bfu(ushort h) {
    union { unsigned u; float f; } v; v.u = ((unsigned)h) << 16; return v.f;
}

// repack weights (d,c,kk) -> B-fragments Wb[(kt*28+nt)*64 + lane][j] (bf16)
__global__ void kPb(const float* __restrict__ w, ushort* __restrict__ Wb) {
    int i = blockIdx.x * 256 + threadIdx.x;   // 28672 total
    if (i < 28672) {
        int j = i & 7;
        int l = (i >> 3) & 63;
        int q = i >> 9;            // kt*28 + nt
        int nt = q % 28, kt = q / 28;
        int k = kt * 32 + 8 * (l >> 4) + j;       // channel c
        int n = nt * 16 + (l & 15);
        int d = n / 7, kk = n - 7 * d;
        Wb[i] = (ushort)(cvt_pk_bf16(w[(d * 64 + k) * 7 + kk], 0.f) & 0xffffu);
    }
}

// fused: dyn-weight GEMM (MFMA bf16) + tanh + 14-tap dot2 contraction + residual + BN1 partials
__global__ __launch_bounds__(256, 4) void kA(const float* __restrict__ x,
                                             const ushort* __restrict__ Wb,
                                             ushort* __restrict__ y,
                                             float* __restrict__ ps,
                                             float* __restrict__ pq) {
    __shared__ ushort xp[22 * 128];      // pair-major [rp][c][s] bf16, 5.5 KB
    __shared__ ushort gsT[448 * 34];     // tanh(G) transposed [n][l'], pad 34 (29.75 KB)
    __shared__ float  red[2][4][64];

    const int tid = threadIdx.x;
    const int w = tid >> 6, l = tid & 63;
    const int b = blockIdx.y;
    const float* xb = x + (long)b * L_ * 64;

    // persistent B-fragments (28 VGPR)
    short8 wreg[7][2];
    #pragma unroll
    for (int i = 0; i < 7; ++i) {
        wreg[i][0] = *(const short8*)&Wb[((w + 4 * i) * 64 + l) * 8];
        wreg[i][1] = *(const short8*)&Wb[((28 + w + 4 * i) * 64 + l) * 8];
    }

    float S = 0.f, Q = 0.f;

    for (int it = 0; it < IT; ++it) {
        const int jt = blockIdx.x * IT + it;
        const int j0 = jt * TJ;
        const int xrow0 = 2 * j0;
        if (it) __syncthreads();     // prev-iter epilogue done before restaging

        // stage 22 row-pairs of x as bf16 pair-major
        #pragma unroll
        for (int st = 0; st < 3; ++st) {
            int p = tid + st * 256;
            if (p < 704) {
                int rp = p >> 5, c0 = (p & 31) * 2;
                int r0 = min(xrow0 + 2 * rp, L_ - 1);
                int r1 = min(xrow0 + 2 * rp + 1, L_ - 1);
                float2 va = *(const float2*)(xb + (long)r0 * 64 + c0);
                float2 vb = *(const float2*)(xb + (long)r1 * 64 + c0);
                uint2 wv;
                wv.x = cvt_pk_bf16(va.x, vb.x);
                wv.y = cvt_pk_bf16(va.y, vb.y);
                *(uint2*)((char*)xp + rp * 256 + c0 * 4) = wv;
            }
        }

        // A-fragments straight from global f32
        short8 afr[2][2];
        #pragma unroll
        for (int mt = 0; mt < 2; ++mt)
            #pragma unroll
            for (int kt = 0; kt < 2; ++kt) {
                int row = min(xrow0 + 12 + mt * 16 + (l & 15), L_ - 1);
                const float* pr = xb + (long)row * 64 + kt * 32 + (l >> 4) * 8;
                float4 v0 = *(const float4*)pr;
                float4 v1 = *(const float4*)(pr + 4);
                uint4 u;
                u.x = cvt_pk_bf16(v0.x, v0.y);
                u.y = cvt_pk_bf16(v0.z, v0.w);
                u.z = cvt_pk_bf16(v1.x, v1.y);
                u.w = cvt_pk_bf16(v1.z, v1.w);
                afr[mt][kt] = *(short8*)&u;
            }

        // MFMA GEMM + tanh -> gsT
        {
            const int col = l & 15;
            const int r0 = 4 * (l >> 4);
            #pragma unroll
            for (int i = 0; i < 7; ++i) {
                const int nt = w + 4 * i;
                f32x4 acc0 = {0.f, 0.f, 0.f, 0.f};
                f32x4 acc1 = {0.f, 0.f, 0.f, 0.f};
                acc0 = __builtin_amdgcn_mfma_f32_16x16x32_bf16(afr[0][0], wreg[i][0], acc0, 0, 0, 0);
                acc0 = __builtin_amdgcn_mfma_f32_16x16x32_bf16(afr[0][1], wreg[i][1], acc0, 0, 0, 0);
                acc1 = __builtin_amdgcn_mfma_f32_16x16x32_bf16(afr[1][0], wreg[i][0], acc1, 0, 0, 0);
                acc1 = __builtin_amdgcn_mfma_f32_16x16x32_bf16(afr[1][1], wreg[i][1], acc1, 0, 0, 0);
                const int n = nt * 16 + col;
                char* base = (char*)gsT + n * 68;
                *(unsigned*)(base + r0 * 2)            = cvt_pk_bf16(fast_tanh(acc0[0]), fast_tanh(acc0[1]));
                *(unsigned*)(base + r0 * 2 + 4)        = cvt_pk_bf16(fast_tanh(acc0[2]), fast_tanh(acc0[3]));
                *(unsigned*)(base + (r0 + 16) * 2)     = cvt_pk_bf16(fast_tanh(acc1[0]), fast_tanh(acc1[1]));
                *(unsigned*)(base + (r0 + 16) * 2 + 4) = cvt_pk_bf16(fast_tanh(acc1[2]), fast_tanh(acc1[3]));
            }
        }
        __syncthreads();

        // epilogue: y = residual + 14 taps via v_dot2_f32_bf16
        #pragma unroll
        for (int ii = 0; ii < 4; ++ii) {
            const int jj = w + 4 * ii;
            const int j = j0 + jj;
            float acc = bfu(*(const ushort*)((const char*)xp + (6 + jj) * 256 + l * 4));
            const char* xbp = (const char*)xp + jj * 256 + l * 4;
            const char* gbp = (const char*)gsT + l * 476 + jj * 4;
            #pragma unroll
            for (int kk = 0; kk < K_; ++kk) {
                unsigned xpr = *(const unsigned*)(xbp + kk * 256);
                unsigned gp  = *(const unsigned*)(gbp + kk * 68);
                asm("v_dot2_f32_bf16 %0, %1, %2, %0" : "+v"(acc) : "v"(xpr), "v"(gp));
            }
            float other = __shfl_xor(acc, 1);
            if (j < T_) {
                if ((l & 1) == 0) {
                    *(unsigned*)((char*)y + ((long)(b * T_ + j)) * 128 + l * 2) = cvt_pk_bf16(acc, other);
                }
                S += acc;
                Q += acc * acc;
            }
        }
    }

    red[0][w][l] = S;
    red[1][w][l] = Q;
    __syncthreads();
    if (tid < 64) {
        float S4 = red[0][0][tid] + red[0][1][tid] + red[0][2][tid] + red[0][3][tid];
        float Q4 = red[1][0][tid] + red[1][1][tid] + red[1][2][tid] + red[1][3][tid];
        int blk = b * NJB + blockIdx.x;
        ps[tid * NBLKA + blk] = S4;
        pq[tid * NBLKA + blk] = Q4;
    }
}

// reduce transposed per-channel partials -> A = rstd*scale, BB = bias - mean*A
__global__ void kB(const float* __restrict__ ps, const float* __restrict__ pq,
                   float* __restrict__ A, float* __restrict__ BB,
                   const float* __restrict__ scale, const float* __restrict__ bias,
                   int nblk, float invN) {
    const int c = blockIdx.x;
    const float* bs = ps + (long)c * nblk;
    const float* bq = pq + (long)c * nblk;
    float S = 0.f, Q = 0.f;
    for (int i = threadIdx.x; i < nblk; i += 256) {
        S += bs[i];
        Q += bq[i];
    }
    for (int o = 32; o > 0; o >>= 1) {
        S += __shfl_down(S, o);
        Q += __shfl_down(Q, o);
    }
    __shared__ float rs[4], rq[4];
    if ((threadIdx.x & 63) == 0) { rs[threadIdx.x >> 6] = S; rq[threadIdx.x >> 6] = Q; }
    __syncthreads();
    if (threadIdx.x == 0) {
        S = rs[0] + rs[1] + rs[2] + rs[3];
        Q = rq[0] + rq[1] + rq[2] + rq[3];
        float m = S * invN;
        float var = Q * invN - m * m;
        float rstd = rsqrtf(var + 1e-5f);
        float a = rstd * scale[c];
        A[c] = a;
        BB[c] = bias[c] - m * a;
    }
}

// precompute A1-folded w_conv B-fragments (once, after kB1)
__global__ void kW(const float* __restrict__ wconv, const float* __restrict__ A1,
                   ushort* __restrict__ Wb2) {
    int i = blockIdx.x * 256 + threadIdx.x;    // 4096 total
    if (i < 4096) {
        int j = i & 7, lane = (i >> 3) & 63, q2 = i >> 9;
        int kt = q2 >> 2, nt = q2 & 3;
        int c = kt * 32 + 8 * (lane >> 4) + j;
        int e = nt * 16 + (lane & 15);
        Wb2[i] = (ushort)(cvt_pk_bf16(A1[c] * wconv[c * 64 + e], 0.f) & 0xffffu);
    }
}

// pass 2a: z' = y_bf16 @ Wb2, BN2 partials only — no LDS staging, frags from global
__global__ __launch_bounds__(256) void kZ(const ushort* __restrict__ y,
                                          const ushort* __restrict__ Wb2,
                                          float* __restrict__ ps2,
                                          float* __restrict__ pq2) {
    __shared__ float red[2][4][64];
    const int tid = threadIdx.x, w = tid >> 6, l = tid & 63;
    short8 bfr[4][2];
    #pragma unroll
    for (int nt = 0; nt < 4; ++nt)
        #pragma unroll
        for (int kt = 0; kt < 2; ++kt)
            bfr[nt][kt] = *(const short8*)&Wb2[((kt * 4 + nt) * 64 + l) * 8];

    float ss[4] = {0.f, 0.f, 0.f, 0.f}, qq[4] = {0.f, 0.f, 0.f, 0.f};
    #pragma unroll
    for (int g2 = 0; g2 < 2; ++g2) {
        long rowg = (long)blockIdx.x * 128 + g2 * 64 + w * 16 + (l & 15);
        short8 a0 = {0, 0, 0, 0, 0, 0, 0, 0};
        short8 a1 = {0, 0, 0, 0, 0, 0, 0, 0};
        if (rowg < M_) {
            const char* yr = (const char*)y + rowg * 128 + (l >> 4) * 16;
            a0 = *(const short8*)yr;
            a1 = *(const short8*)(yr + 64);
        }
        #pragma unroll
        for (int nt = 0; nt < 4; ++nt) {
            f32x4 acc = {0.f, 0.f, 0.f, 0.f};
            acc = __builtin_amdgcn_mfma_f32_16x16x32_bf16(a0, bfr[nt][0], acc, 0, 0, 0);
            acc = __builtin_amdgcn_mfma_f32_16x16x32_bf16(a1, bfr[nt][1], acc, 0, 0, 0);
            #pragma unroll
            for (int i = 0; i < 4; ++i) { ss[nt] += acc[i]; qq[nt] += acc[i] * acc[i]; }
        }
    }
    #pragma unroll
    for (int nt = 0; nt < 4; ++nt) {
        float s2 = ss[nt] + __shfl_xor(ss[nt], 16); s2 += __shfl_xor(s2, 32);
        float q2 = qq[nt] + __shfl_xor(qq[nt], 16); q2 += __shfl_xor(q2, 32);
        if (l < 16) { red[0][w][nt * 16 + l] = s2; red[1][w][nt * 16 + l] = q2; }
    }
    __syncthreads();
    if (tid < 64) {
        float S = red[0][0][tid] + red[0][1][tid] + red[0][2][tid] + red[0][3][tid];
        float Q = red[1][0][tid] + red[1][1][tid] + red[1][2][tid] + red[1][3][tid];
        ps2[tid * NBZ + blockIdx.x] = S;
        pq2[tid * NBZ + blockIdx.x] = Q;
    }
}

// pass 2b: recompute z' (identical MFMA), out = (A1*y+BB1) + gelu(A2*z'+BB2) — no LDS
__global__ __launch_bounds__(256) void kE(const ushort* __restrict__ y,
                                          const ushort* __restrict__ Wb2,
                                          const float* __restrict__ A1,
                                          const float* __restrict__ B1,
                                          const float* __restrict__ A2,
                                          const float* __restrict__ B2,
                                          float* __restrict__ out) {
    const int tid = threadIdx.x, w = tid >> 6, l = tid & 63;
    short8 bfr[4][2];
    #pragma unroll
    for (int nt = 0; nt < 4; ++nt)
        #pragma unroll
        for (int kt = 0; kt < 2; ++kt)
            bfr[nt][kt] = *(const short8*)&Wb2[((kt * 4 + nt) * 64 + l) * 8];

    const long row0 = (long)blockIdx.x * 64;
    long rowg = row0 + w * 16 + (l & 15);
    short8 a0 = {0, 0, 0, 0, 0, 0, 0, 0};
    short8 a1 = {0, 0, 0, 0, 0, 0, 0, 0};
    if (rowg < M_) {
        const char* yr = (const char*)y + rowg * 128 + (l >> 4) * 16;
        a0 = *(const short8*)yr;
        a1 = *(const short8*)(yr + 64);
    }
    #pragma unroll
    for (int nt = 0; nt < 4; ++nt) {
        f32x4 acc = {0.f, 0.f, 0.f, 0.f};
        acc = __builtin_amdgcn_mfma_f32_16x16x32_bf16(a0, bfr[nt][0], acc, 0, 0, 0);
        acc = __builtin_amdgcn_mfma_f32_16x16x32_bf16(a1, bfr[nt][1], acc, 0, 0, 0);
        const int e = nt * 16 + (l & 15);
        const float a1c = A1[e], b1c = B1[e], a2c = A2[e], b2c = B2[e];
        #pragma unroll
        for (int i = 0; i < 4; ++i) {
            long gr = row0 + w * 16 + 4 * (l >> 4) + i;
            if (gr < M_) {
                float yv = bfu(*(const ushort*)((const char*)y + gr * 128 + e * 2));
                float zb = a2c * acc[i] + b2c;
                out[gr * 64 + e] = fmaf(a1c, yv, b1c) + gelu_tanh(zb);
            }
        }
    }
}

extern "C" void kernel_launch(void* const* d_in, const int* in_sizes, int n_in,
                              void* d_out, int out_size, void* d_ws, size_t ws_size,
                              hipStream_t stream) {
    const float* x       = (const float*)d_in[0];
    const float* weights = (const float*)d_in[1];
    const float* w_conv  = (const float*)d_in[2];
    const float* scale1  = (const float*)d_in[3];
    const float* bias1   = (const float*)d_in[4];
    const float* scale2  = (const float*)d_in[5];
    const float* bias2   = (const float*)d_in[6];
    float* out = (float*)d_out;
    float* ws  = (float*)d_ws;

    ushort* Wb  = (ushort*)(ws + OF_WB);
    ushort* Wb2 = (ushort*)(ws + OF_WB2);
    ushort* yb  = (ushort*)(ws + OF_Y);
    float* ps1 = ws + OF_PS1;
    float* pq1 = ws + OF_PQ1;
    float* ps2 = ws + OF_PS2;
    float* pq2 = ws + OF_PQ2;
    float* A1  = ws + OF_C1;
    float* BB1 = ws + OF_C1 + 64;
    float* A2  = ws + OF_C2;
    float* BB2 = ws + OF_C2 + 64;

    const float invN = 1.f / (float)M_;

    kPb<<<112, 256, 0, stream>>>(weights, Wb);
    kA<<<dim3(NJB, B_), 256, 0, stream>>>(x, Wb, yb, ps1, pq1);
    kB<<<64, 256, 0, stream>>>(ps1, pq1, A1, BB1, scale1, bias1, NBLKA, invN);
    kW<<<16, 256, 0, stream>>>(w_conv, A1, Wb2);
    kZ<<<NBZ, 256, 0, stream>>>(yb, Wb2, ps2, pq2);
    kB<<<64, 256, 0, stream>>>(ps2, pq2, A2, BB2, scale2, bias2, NBZ, invN);
    kE<<<NBE, 256, 0, stream>>>(yb, Wb2, A1, BB1, A2, BB2, out);
}

// Round 6
// 59.211 us; speedup vs baseline: 4.5500x; 1.0267x over previous
//
#include <hip/hip_runtime.h>
#include <hip/hip_bf16.h>

#define B_ 4
#define L_ 32768
#define C_ 64
#define K_ 7
#define T_ 16378              // (L - 2K)/2 + 1
#define M_ (B_*T_)            // 65512 rows
#define TJ 16                 // output positions per j-tile
#define IT 4                  // j-tiles per kA block
#define NJB 256               // grid.x of kA  (NJB*IT*TJ = 16384 >= T_)
#define NBLKA (B_*NJB)        // 1024 partial sets
#define NBZ 512               // kZ blocks (x128 rows)
#define NBE 1024              // kE blocks (x64 rows)

// workspace layout in floats
#define OF_WB   0                        // Wb: 28672 ushorts = 14336 floats
#define OF_WB2  14336                    // Wb2: 4096 ushorts = 2048 floats
#define OF_Y    16384                    // y bf16: M_*64 ushorts = M_*32 floats
#define OF_PS1  (OF_Y + M_*32)           // [c][NBLKA]
#define OF_PQ1  (OF_PS1 + 64*NBLKA)
#define OF_PS2  (OF_PQ1 + 64*NBLKA)      // [c][NBZ]
#define OF_PQ2  (OF_PS2 + 64*NBZ)
#define OF_C1   (OF_PQ2 + 64*NBZ)        // A1[64], BB1[64]
#define OF_C2   (OF_C1 + 128)            // A2[64], BB2[64]

typedef __attribute__((ext_vector_type(8))) short short8;
typedef __attribute__((ext_vector_type(4))) float f32x4;

__device__ __forceinline__ unsigned cvt_pk_bf16(float a, float b) {
    unsigned r;
    asm("v_cvt_pk_bf16_f32 %0, %1, %2" : "=v"(r) : "v"(a), "v"(b));
    return r;   // lo = bf16(a), hi = bf16(b)
}

__device__ __forceinline__ float fast_tanh(float x) {
    float e = __builtin_amdgcn_exp2f(x * 2.885390082f);   // 2*log2(e)
    return __builtin_fmaf(-2.f, __builtin_amdgcn_rcpf(1.f + e), 1.f);
}

__device__ __forceinline__ float gelu_tanh(float v) {
    float u = 0.7978845608028654f * (v + 0.044715f * v * v * v);
    return 0.5f * v * (1.f + fast_tanh(u));
}

__device__ __forceinline__ float bfu(ushort h) {
    union { unsigned u; float f; } v; v.u = ((unsigned)h) << 16; return v.f;
}
__device__ __forceinline__ float bflo(unsigned p) {
    union { unsigned u; float f; } v; v.u = p << 16; return v.f;
}

// repack weights (d,c,kk) -> B-fragments Wb[(kt*28+nt)*64 + lane][j] (bf16)
__global__ void kPb(const float* __restrict__ w, ushort* __restrict__ Wb) {
    int i = blockIdx.x * 256 + threadIdx.x;   // 28672 total
    if (i < 28672) {
        int j = i & 7;
        int l = (i >> 3) & 63;
        int q = i >> 9;            // kt*28 + nt
        int nt = q % 28, kt = q / 28;
        int k = kt * 32 + 8 * (l >> 4) + j;       // channel c
        int n = nt * 16 + (l & 15);
        int d = n / 7, kk = n - 7 * d;
        Wb[i] = (ushort)(cvt_pk_bf16(w[(d * 64 + k) * 7 + kk], 0.f) & 0xffffu);
    }
}

// fused: dyn-weight GEMM (MFMA) + tanh + pair-epilogue taps + residual + BN1 partials
__global__ __launch_bounds__(256, 4) void kA(const float* __restrict__ x,
                                             const ushort* __restrict__ Wb,
                                             ushort* __restrict__ y,
                                             float* __restrict__ ps,
                                             float* __restrict__ pq) {
    __shared__ ushort xp[22 * 128];      // pair-major [rp][c][s] bf16, 5632 B
    __shared__ ushort gsT[448 * 36];     // tanh(G) transposed [n][l'], 72B stride, 32256 B
    __shared__ float  red[2][4][64];     // 2048 B   (total 39936 B -> 4 blocks/CU)

    const int tid = threadIdx.x;
    const int w = tid >> 6, l = tid & 63;
    const int b = blockIdx.y;
    const float* xb = x + (long)b * L_ * 64;

    // persistent B-fragments
    short8 wreg[7][2];
    #pragma unroll
    for (int i = 0; i < 7; ++i) {
        wreg[i][0] = *(const short8*)&Wb[((w + 4 * i) * 64 + l) * 8];
        wreg[i][1] = *(const short8*)&Wb[((28 + w + 4 * i) * 64 + l) * 8];
    }

    float S = 0.f, Q = 0.f;

    for (int it = 0; it < IT; ++it) {
        const int jt = blockIdx.x * IT + it;
        const int j0 = jt * TJ;
        const int xrow0 = 2 * j0;
        if (it) __syncthreads();     // prev epilogue reads done before restage

        // stage 22 row-pairs of x as bf16 pair-major
        #pragma unroll
        for (int st = 0; st < 3; ++st) {
            int p = tid + st * 256;
            if (p < 704) {
                int rp = p >> 5, c0 = (p & 31) * 2;
                int r0 = min(xrow0 + 2 * rp, L_ - 1);
                int r1 = min(xrow0 + 2 * rp + 1, L_ - 1);
                float2 va = *(const float2*)(xb + (long)r0 * 64 + c0);
                float2 vb = *(const float2*)(xb + (long)r1 * 64 + c0);
                uint2 wv;
                wv.x = cvt_pk_bf16(va.x, vb.x);
                wv.y = cvt_pk_bf16(va.y, vb.y);
                *(uint2*)((char*)xp + rp * 256 + c0 * 4) = wv;
            }
        }

        // A-fragments straight from global f32 (L1-hot)
        short8 afr[2][2];
        #pragma unroll
        for (int mt = 0; mt < 2; ++mt)
            #pragma unroll
            for (int kt = 0; kt < 2; ++kt) {
                int row = min(xrow0 + 12 + mt * 16 + (l & 15), L_ - 1);
                const float* pr = xb + (long)row * 64 + kt * 32 + (l >> 4) * 8;
                float4 v0 = *(const float4*)pr;
                float4 v1 = *(const float4*)(pr + 4);
                uint4 u;
                u.x = cvt_pk_bf16(v0.x, v0.y);
                u.y = cvt_pk_bf16(v0.z, v0.w);
                u.z = cvt_pk_bf16(v1.x, v1.y);
                u.w = cvt_pk_bf16(v1.z, v1.w);
                afr[mt][kt] = *(short8*)&u;
            }

        // MFMA GEMM + tanh -> gsT (uint2 writes)
        {
            const int col = l & 15;
            const int r0 = 4 * (l >> 4);
            #pragma unroll
            for (int i = 0; i < 7; ++i) {
                const int nt = w + 4 * i;
                f32x4 acc0 = {0.f, 0.f, 0.f, 0.f};
                f32x4 acc1 = {0.f, 0.f, 0.f, 0.f};
                acc0 = __builtin_amdgcn_mfma_f32_16x16x32_bf16(afr[0][0], wreg[i][0], acc0, 0, 0, 0);
                acc0 = __builtin_amdgcn_mfma_f32_16x16x32_bf16(afr[0][1], wreg[i][1], acc0, 0, 0, 0);
                acc1 = __builtin_amdgcn_mfma_f32_16x16x32_bf16(afr[1][0], wreg[i][0], acc1, 0, 0, 0);
                acc1 = __builtin_amdgcn_mfma_f32_16x16x32_bf16(afr[1][1], wreg[i][1], acc1, 0, 0, 0);
                const int n = nt * 16 + col;
                char* base = (char*)gsT + n * 72;
                uint2 lo, hi;
                lo.x = cvt_pk_bf16(fast_tanh(acc0[0]), fast_tanh(acc0[1]));
                lo.y = cvt_pk_bf16(fast_tanh(acc0[2]), fast_tanh(acc0[3]));
                hi.x = cvt_pk_bf16(fast_tanh(acc1[0]), fast_tanh(acc1[1]));
                hi.y = cvt_pk_bf16(fast_tanh(acc1[2]), fast_tanh(acc1[3]));
                *(uint2*)(base + r0 * 2)      = lo;   // rows r0..r0+3
                *(uint2*)(base + 32 + r0 * 2) = hi;   // rows r0+16..r0+19
            }
        }
        __syncthreads();

        // epilogue: pairs (jj0, jj0+1); 8 xpr b32 + 7 gp b64 per pair
        #pragma unroll
        for (int jp = 0; jp < 2; ++jp) {
            const int jj0 = 2 * w + 8 * jp;
            unsigned xv[8];
            #pragma unroll
            for (int k2 = 0; k2 < 8; ++k2)
                xv[k2] = *(const unsigned*)((const char*)xp + (jj0 + k2) * 256 + l * 4);
            float acc0 = bflo(xv[6]);       // residual x[12+2jj0][d]
            float acc1 = bflo(xv[7]);       // residual x[12+2jj1][d]
            const char* gbp = (const char*)gsT + l * 504 + jj0 * 4;
            #pragma unroll
            for (int kk = 0; kk < K_; ++kk) {
                uint2 gp = *(const uint2*)(gbp + kk * 72);
                asm("v_dot2_f32_bf16 %0, %1, %2, %0" : "+v"(acc0) : "v"(xv[kk]),     "v"(gp.x));
                asm("v_dot2_f32_bf16 %0, %1, %2, %0" : "+v"(acc1) : "v"(xv[kk + 1]), "v"(gp.y));
            }
            float o0 = __shfl_xor(acc0, 1);
            float o1 = __shfl_xor(acc1, 1);
            const int j = j0 + jj0;
            if (j < T_) {                    // wave-uniform; jj1=j+1 < T_ too (T_ even)
                if ((l & 1) == 0) {
                    *(unsigned*)((char*)y + (long)(b * T_ + j) * 128 + l * 2)     = cvt_pk_bf16(acc0, o0);
                    *(unsigned*)((char*)y + (long)(b * T_ + j + 1) * 128 + l * 2) = cvt_pk_bf16(acc1, o1);
                }
                S += acc0 + acc1;
                Q += acc0 * acc0 + acc1 * acc1;
            }
        }
    }

    red[0][w][l] = S;
    red[1][w][l] = Q;
    __syncthreads();
    if (tid < 64) {
        float S4 = red[0][0][tid] + red[0][1][tid] + red[0][2][tid] + red[0][3][tid];
        float Q4 = red[1][0][tid] + red[1][1][tid] + red[1][2][tid] + red[1][3][tid];
        int blk = b * NJB + blockIdx.x;
        ps[tid * NBLKA + blk] = S4;
        pq[tid * NBLKA + blk] = Q4;
    }
}

// reduce transposed per-channel partials -> A = rstd*scale, BB = bias - mean*A
__global__ void kB(const float* __restrict__ ps, const float* __restrict__ pq,
                   float* __restrict__ A, float* __restrict__ BB,
                   const float* __restrict__ scale, const float* __restrict__ bias,
                   int nblk, float invN) {
    const int c = blockIdx.x;
    const float* bs = ps + (long)c * nblk;
    const float* bq = pq + (long)c * nblk;
    float S = 0.f, Q = 0.f;
    for (int i = threadIdx.x; i < nblk; i += 256) {
        S += bs[i];
        Q += bq[i];
    }
    for (int o = 32; o > 0; o >>= 1) {
        S += __shfl_down(S, o);
        Q += __shfl_down(Q, o);
    }
    __shared__ float rs[4], rq[4];
    if ((threadIdx.x & 63) == 0) { rs[threadIdx.x >> 6] = S; rq[threadIdx.x >> 6] = Q; }
    __syncthreads();
    if (threadIdx.x == 0) {
        S = rs[0] + rs[1] + rs[2] + rs[3];
        Q = rq[0] + rq[1] + rq[2] + rq[3];
        float m = S * invN;
        float var = Q * invN - m * m;
        float rstd = rsqrtf(var + 1e-5f);
        float a = rstd * scale[c];
        A[c] = a;
        BB[c] = bias[c] - m * a;
    }
}

// precompute A1-folded w_conv B-fragments
__global__ void kW(const float* __restrict__ wconv, const float* __restrict__ A1,
                   ushort* __restrict__ Wb2) {
    int i = blockIdx.x * 256 + threadIdx.x;    // 4096 total
    if (i < 4096) {
        int j = i & 7, lane = (i >> 3) & 63, q2 = i >> 9;
        int kt = q2 >> 2, nt = q2 & 3;
        int c = kt * 32 + 8 * (lane >> 4) + j;
        int e = nt * 16 + (lane & 15);
        Wb2[i] = (ushort)(cvt_pk_bf16(A1[c] * wconv[c * 64 + e], 0.f) & 0xffffu);
    }
}

// pass 2a: z' = y_bf16 @ Wb2, BN2 partials only — frags from global, no LDS staging
__global__ __launch_bounds__(256) void kZ(const ushort* __restrict__ y,
                                          const ushort* __restrict__ Wb2,
                                          float* __restrict__ ps2,
                                          float* __restrict__ pq2) {
    __shared__ float red[2][4][64];
    const int tid = threadIdx.x, w = tid >> 6, l = tid & 63;
    short8 bfr[4][2];
    #pragma unroll
    for (int nt = 0; nt < 4; ++nt)
        #pragma unroll
        for (int kt = 0; kt < 2; ++kt)
            bfr[nt][kt] = *(const short8*)&Wb2[((kt * 4 + nt) * 64 + l) * 8];

    float ss[4] = {0.f, 0.f, 0.f, 0.f}, qq[4] = {0.f, 0.f, 0.f, 0.f};
    #pragma unroll
    for (int g2 = 0; g2 < 2; ++g2) {
        long rowg = (long)blockIdx.x * 128 + g2 * 64 + w * 16 + (l & 15);
        short8 a0 = {0, 0, 0, 0, 0, 0, 0, 0};
        short8 a1 = {0, 0, 0, 0, 0, 0, 0, 0};
        if (rowg < M_) {
            const char* yr = (const char*)y + rowg * 128 + (l >> 4) * 16;
            a0 = *(const short8*)yr;
            a1 = *(const short8*)(yr + 64);
        }
        #pragma unroll
        for (int nt = 0; nt < 4; ++nt) {
            f32x4 acc = {0.f, 0.f, 0.f, 0.f};
            acc = __builtin_amdgcn_mfma_f32_16x16x32_bf16(a0, bfr[nt][0], acc, 0, 0, 0);
            acc = __builtin_amdgcn_mfma_f32_16x16x32_bf16(a1, bfr[nt][1], acc, 0, 0, 0);
            #pragma unroll
            for (int i = 0; i < 4; ++i) { ss[nt] += acc[i]; qq[nt] += acc[i] * acc[i]; }
        }
    }
    #pragma unroll
    for (int nt = 0; nt < 4; ++nt) {
        float s2 = ss[nt] + __shfl_xor(ss[nt], 16); s2 += __shfl_xor(s2, 32);
        float q2 = qq[nt] + __shfl_xor(qq[nt], 16); q2 += __shfl_xor(q2, 32);
        if (l < 16) { red[0][w][nt * 16 + l] = s2; red[1][w][nt * 16 + l] = q2; }
    }
    __syncthreads();
    if (tid < 64) {
        float S = red[0][0][tid] + red[0][1][tid] + red[0][2][tid] + red[0][3][tid];
        float Q = red[1][0][tid] + red[1][1][tid] + red[1][2][tid] + red[1][3][tid];
        ps2[tid * NBZ + blockIdx.x] = S;
        pq2[tid * NBZ + blockIdx.x] = Q;
    }
}

// pass 2b: recompute z' -> LDS transpose -> coalesced fused epilogue
__global__ __launch_bounds__(256) void kE(const ushort* __restrict__ y,
                                          const ushort* __restrict__ Wb2,
                                          const float* __restrict__ A1,
                                          const float* __restrict__ B1,
                                          const float* __restrict__ A2,
                                          const float* __restrict__ B2,
                                          float* __restrict__ out) {
    __shared__ float zs[64][68];     // padded, 17408 B
    __shared__ float cf[4][64];
    const int tid = threadIdx.x, w = tid >> 6, l = tid & 63;

    if (tid < 64)       cf[0][tid] = A1[tid];
    else if (tid < 128) cf[1][tid - 64] = B1[tid - 64];
    else if (tid < 192) cf[2][tid - 128] = A2[tid - 128];
    else                cf[3][tid - 192] = B2[tid - 192];

    short8 bfr[4][2];
    #pragma unroll
    for (int nt = 0; nt < 4; ++nt)
        #pragma unroll
        for (int kt = 0; kt < 2; ++kt)
            bfr[nt][kt] = *(const short8*)&Wb2[((kt * 4 + nt) * 64 + l) * 8];

    const long row0 = (long)blockIdx.x * 64;
    long rowg = row0 + w * 16 + (l & 15);
    short8 a0 = {0, 0, 0, 0, 0, 0, 0, 0};
    short8 a1 = {0, 0, 0, 0, 0, 0, 0, 0};
    if (rowg < M_) {
        const char* yr = (const char*)y + rowg * 128 + (l >> 4) * 16;
        a0 = *(const short8*)yr;
        a1 = *(const short8*)(yr + 64);
    }
    #pragma unroll
    for (int nt = 0; nt < 4; ++nt) {
        f32x4 acc = {0.f, 0.f, 0.f, 0.f};
        acc = __builtin_amdgcn_mfma_f32_16x16x32_bf16(a0, bfr[nt][0], acc, 0, 0, 0);
        acc = __builtin_amdgcn_mfma_f32_16x16x32_bf16(a1, bfr[nt][1], acc, 0, 0, 0);
        const int e = nt * 16 + (l & 15);
        #pragma unroll
        for (int i = 0; i < 4; ++i)
            zs[w * 16 + 4 * (l >> 4) + i][e] = acc[i];
    }
    __syncthreads();

    // phase 2: fully-coalesced fused epilogue
    #pragma unroll
    for (int i = 0; i < 4; ++i) {
        int rloc = i * 16 + (tid >> 4);
        long gr = row0 + rloc;
        int ch0 = (tid & 15) * 4;
        if (gr < M_) {
            uint2 yp = *(const uint2*)((const char*)y + gr * 128 + ch0 * 2);
            float4 z4 = *(const float4*)&zs[rloc][ch0];
            float yv0 = bflo(yp.x), yv1 = bfu((ushort)(yp.x >> 16));
            float yv2 = bflo(yp.y), yv3 = bfu((ushort)(yp.y >> 16));
            float4 o;
            o.x = fmaf(cf[0][ch0 + 0], yv0, cf[1][ch0 + 0]) + gelu_tanh(fmaf(cf[2][ch0 + 0], z4.x, cf[3][ch0 + 0]));
            o.y = fmaf(cf[0][ch0 + 1], yv1, cf[1][ch0 + 1]) + gelu_tanh(fmaf(cf[2][ch0 + 1], z4.y, cf[3][ch0 + 1]));
            o.z = fmaf(cf[0][ch0 + 2], yv2, cf[1][ch0 + 2]) + gelu_tanh(fmaf(cf[2][ch0 + 2], z4.z, cf[3][ch0 + 2]));
            o.w = fmaf(cf[0][ch0 + 3], yv3, cf[1][ch0 + 3]) + gelu_tanh(fmaf(cf[2][ch0 + 3], z4.w, cf[3][ch0 + 3]));
            *(float4*)&out[gr * 64 + ch0] = o;
        }
    }
}

extern "C" void kernel_launch(void* const* d_in, const int* in_sizes, int n_in,
                              void* d_out, int out_size, void* d_ws, size_t ws_size,
                              hipStream_t stream) {
    const float* x       = (const float*)d_in[0];
    const float* weights = (const float*)d_in[1];
    const float* w_conv  = (const float*)d_in[2];
    const float* scale1  = (const float*)d_in[3];
    const float* bias1   = (const float*)d_in[4];
    const float* scale2  = (const float*)d_in[5];
    const float* bias2   = (const float*)d_in[6];
    float* out = (float*)d_out;
    float* ws  = (float*)d_ws;

    ushort* Wb  = (ushort*)(ws + OF_WB);
    ushort* Wb2 = (ushort*)(ws + OF_WB2);
    ushort* yb  = (ushort*)(ws + OF_Y);
    float* ps1 = ws + OF_PS1;
    float* pq1 = ws + OF_PQ1;
    float* ps2 = ws + OF_PS2;
    float* pq2 = ws + OF_PQ2;
    float* A1  = ws + OF_C1;
    float* BB1 = ws + OF_C1 + 64;
    float* A2  = ws + OF_C2;
    float* BB2 = ws + OF_C2 + 64;

    const float invN = 1.f / (float)M_;

    kPb<<<112, 256, 0, stream>>>(weights, Wb);
    kA<<<dim3(NJB, B_), 256, 0, stream>>>(x, Wb, yb, ps1, pq1);
    kB<<<64, 256, 0, stream>>>(ps1, pq1, A1, BB1, scale1, bias1, NBLKA, invN);
    kW<<<16, 256, 0, stream>>>(w_conv, A1, Wb2);
    kZ<<<NBZ, 256, 0, stream>>>(yb, Wb2, ps2, pq2);
    kB<<<64, 256, 0, stream>>>(ps2, pq2, A2, BB2, scale2, bias2, NBZ, invN);
    kE<<<NBE, 256, 0, stream>>>(yb, Wb2, A1, BB1, A2, BB2, out);
}